// Round 18
// baseline (1011.510 us; speedup 1.0000x reference)
//
#include <hip/hip_runtime.h>

#define B_  256
#define N_  196
#define D_  2048
#define F_  512
#define ROWS (B_*N_)   // 50176
#define CAND 8
#define PROWS 208
#define PELEMS (PROWS*32)   // 6656 fp16 per panel

typedef _Float16 f16x8 __attribute__((ext_vector_type(8)));
typedef _Float16 f16x4 __attribute__((ext_vector_type(4)));
typedef float    f32x4 __attribute__((ext_vector_type(4)));

static __device__ __forceinline__ float wave_reduce_sum(float v) {
#pragma unroll
  for (int off = 32; off > 0; off >>= 1) v += __shfl_xor(v, off);
  return v;
}

static __device__ __forceinline__ double wave_reduce_sum_d(double v) {
#pragma unroll
  for (int off = 32; off > 0; off >>= 1) v += __shfl_xor(v, off);
  return v;
}

// numpy pairwise-sum replica of sum(x*x) (R5-validated, bit-exact).
static __device__ __forceinline__ float np_chain16(const float* __restrict__ x, int h) {
  int base = (h >> 3) * 128 + (h & 7);
  float t0 = x[base];
  float r = __fmul_rn(t0, t0);
#pragma unroll
  for (int i = 1; i < 16; ++i) {
    float t = x[base + 8 * i];
    r = __fadd_rn(r, __fmul_rn(t, t));
  }
  return r;
}
static __device__ __forceinline__ float np_sq_row(const float* __restrict__ x, int lane) {
  float ra = np_chain16(x, lane);
  float rb = np_chain16(x, lane + 64);
#pragma unroll
  for (int off = 1; off <= 4; off <<= 1) {
    ra = __fadd_rn(ra, __shfl_xor(ra, off));
    rb = __fadd_rn(rb, __shfl_xor(rb, off));
  }
  float lf[16];
#pragma unroll
  for (int L = 0; L < 8; ++L) { lf[L] = __shfl(ra, L * 8); lf[8 + L] = __shfl(rb, L * 8); }
  float b8[8];
#pragma unroll
  for (int t = 0; t < 8; ++t) b8[t] = __fadd_rn(lf[2 * t], lf[2 * t + 1]);
  float c4[4];
#pragma unroll
  for (int t = 0; t < 4; ++t) c4[t] = __fadd_rn(b8[2 * t], b8[2 * t + 1]);
  return __fadd_rn(__fadd_rn(c4[0], c4[1]), __fadd_rn(c4[2], c4[3]));
}

// ---------- W [K][F] fp32  ->  Wt2 k-panels: [K/32][F][32] fp16 ----------
__global__ __launch_bounds__(256) void wtrans_kernel(const float* __restrict__ W,
                                                     _Float16* __restrict__ Wt2) {
  __shared__ float T[64][68];
  int k0 = blockIdx.x * 64;
  int f0 = blockIdx.y * 64;
  int tid = threadIdx.x;
  int c = tid & 63;
  int r4 = tid >> 6;
#pragma unroll
  for (int p = 0; p < 16; ++p) {
    int r = p * 4 + r4;
    T[r][c] = W[(size_t)(k0 + r) * F_ + f0 + c];
  }
  __syncthreads();
#pragma unroll
  for (int p = 0; p < 16; ++p) {
    int fr = p * 4 + r4;
    int kg = k0 + c;
    Wt2[(size_t)(kg >> 5) * F_ * 32 + (size_t)(f0 + fr) * 32 + (kg & 31)] = (_Float16)T[c][fr];
  }
}

// ---------- panelize: X fp32 -> Xh fp16 k-panels + approx sqg. No LDS/barriers. ----------
__global__ __launch_bounds__(256) void panelize_kernel(const float* __restrict__ X,
                                                       _Float16* __restrict__ Xh,
                                                       float* __restrict__ sqg) {
  const int tid = threadIdx.x;
  const int ar  = tid >> 3;            // 0..31 (row within block)
  const int ak  = (tid & 7) * 4;       // 0,4,...,28
  const int lane = tid & 63;
  const int grow = blockIdx.x * 32 + ar;
  const int bb = grow / N_;
  const int rl = grow - bb * N_;
  const float* xr = X + (size_t)grow * D_;
  _Float16* pRow = Xh + (size_t)bb * 64 * PELEMS + (size_t)rl * 32 + ak;
  float sqp = 0.f;
#pragma unroll 4
  for (int t = 0; t < 64; ++t) {
    float4 v = *(const float4*)&xr[t * 32 + ak];
    sqp += v.x * v.x + v.y * v.y + v.z * v.z + v.w * v.w;
    f16x4 h4 = { (_Float16)v.x, (_Float16)v.y, (_Float16)v.z, (_Float16)v.w };
    *(f16x4*)(pRow + (size_t)t * PELEMS) = h4;
  }
  sqp += __shfl_xor(sqp, 1); sqp += __shfl_xor(sqp, 2); sqp += __shfl_xor(sqp, 4);
  if ((lane & 7) == 0) sqg[grow] = sqp;
}

// ---------- h_gemm_p: barrier-free GEMM from Xh panels (A) + Wt2 panels (B).
//            grid (2, 784): x = column half (256 cols), y = m-tile. Fused e-partials. ----------
__global__ __launch_bounds__(256) void h_gemm_p(const _Float16* __restrict__ Xh,
                                                const _Float16* __restrict__ Wt2,
                                                const float* __restrict__ As,
                                                const float* __restrict__ Ad,
                                                float* __restrict__ H,
                                                float* __restrict__ esp,
                                                float* __restrict__ edp) {
  __shared__ float eS[64][4];
  __shared__ float eD[64][4];
  const int mBase = blockIdx.y * 64;
  const int half  = blockIdx.x;        // 0 or 1
  const int nBase = half * 256;
  const int tid  = threadIdx.x;
  const int lane = tid & 63;
  const int wave = tid >> 6;           // 0..3, owns cols nBase + wave*64..+63
  const int fr_row = lane & 15;
  const int fr_k   = (lane >> 4) * 8;
  f32x4 acc[4][4] = {};

  // per-m A-fragment base pointers into Xh panels (per-lane)
  const _Float16* pA[4];
#pragma unroll
  for (int m = 0; m < 4; ++m) {
    int rg = mBase + m * 16 + fr_row;
    int bb = rg / N_;
    int rl = rg - bb * N_;
    pA[m] = Xh + (size_t)bb * 64 * PELEMS + (size_t)rl * 32 + fr_k;
  }
  const _Float16* Bb = Wt2 + (size_t)(nBase + wave * 64 + fr_row) * 32 + fr_k;
  const size_t PSTRIDE = (size_t)F_ * 32;

#pragma unroll 2
  for (int t = 0; t < 64; ++t) {
    const size_t po = (size_t)t * PELEMS;
    const _Float16* bp = Bb + (size_t)t * PSTRIDE;
    f16x8 af[4], bf[4];
#pragma unroll
    for (int m = 0; m < 4; ++m) af[m] = *(const f16x8*)(pA[m] + po);
#pragma unroll
    for (int n = 0; n < 4; ++n) bf[n] = *(const f16x8*)&bp[(size_t)n * 512];
#pragma unroll
    for (int m = 0; m < 4; ++m)
#pragma unroll
      for (int n = 0; n < 4; ++n)
        acc[m][n] = __builtin_amdgcn_mfma_f32_16x16x32_f16(af[m], bf[n], acc[m][n], 0, 0, 0);
  }

  // fused e-partials over this wave's 64 cols
  {
    float as_v[4], ad_v[4];
#pragma unroll
    for (int n = 0; n < 4; ++n) {
      int col = nBase + wave * 64 + n * 16 + (lane & 15);
      as_v[n] = As[col]; ad_v[n] = Ad[col];
    }
#pragma unroll
    for (int m = 0; m < 4; ++m) {
#pragma unroll
      for (int i = 0; i < 4; ++i) {
        float ps = 0.f, pd = 0.f;
#pragma unroll
        for (int n = 0; n < 4; ++n) {
          ps += acc[m][n][i] * as_v[n];
          pd += acc[m][n][i] * ad_v[n];
        }
#pragma unroll
        for (int off = 1; off <= 8; off <<= 1) {
          ps += __shfl_xor(ps, off);
          pd += __shfl_xor(pd, off);
        }
        if ((lane & 15) == 0) {
          int row_loc = (lane >> 4) * 4 + i + m * 16;
          eS[row_loc][wave] = ps;
          eD[row_loc][wave] = pd;
        }
      }
    }
  }
  __syncthreads();
  if (tid < 64) {
    float s = eS[tid][0] + eS[tid][1] + eS[tid][2] + eS[tid][3];
    float d = eD[tid][0] + eD[tid][1] + eD[tid][2] + eD[tid][3];
    esp[(size_t)half * ROWS + mBase + tid] = s;
    edp[(size_t)half * ROWS + mBase + tid] = d;
  }

  const int orow0 = mBase + (lane >> 4) * 4;
#pragma unroll
  for (int m = 0; m < 4; ++m) {
#pragma unroll
    for (int n = 0; n < 4; ++n) {
      int col = nBase + wave * 64 + n * 16 + (lane & 15);
#pragma unroll
      for (int i = 0; i < 4; ++i)
        H[(size_t)(orow0 + m * 16 + i) * F_ + col] = acc[m][n][i];
    }
  }
}

// ---------- fallback: h_gemm R12 + e_kernel (validated) ----------
__global__ __launch_bounds__(256, 3) void h_gemm(const float* __restrict__ X,
                                                 const _Float16* __restrict__ Wt2,
                                                 float* __restrict__ H) {
  __shared__ _Float16 Al[2][64][40];
  const int mBase = blockIdx.y * 64;
  const int nBase = blockIdx.x * 256;
  const int tid  = threadIdx.x;
  const int lane = tid & 63;
  const int wave = tid >> 6;
  const int fr_row = lane & 15;
  const int fr_k   = (lane >> 4) * 8;
  const int ar = tid >> 2;
  const int ak = (tid & 3) * 8;
  f32x4 acc[4][4] = {};

  const _Float16* Bb = Wt2 + (size_t)(nBase + wave * 64 + fr_row) * 32 + fr_k;
  const size_t PSTRIDE = (size_t)F_ * 32;

  f16x8 bf[4];
#pragma unroll
  for (int n = 0; n < 4; ++n) bf[n] = *(const f16x8*)&Bb[(size_t)n * 512];

  {
    float4 a0 = *(const float4*)&X[(size_t)(mBase + ar) * D_ + ak];
    float4 a1 = *(const float4*)&X[(size_t)(mBase + ar) * D_ + ak + 4];
    f16x8 ah = { (_Float16)a0.x, (_Float16)a0.y, (_Float16)a0.z, (_Float16)a0.w,
                 (_Float16)a1.x, (_Float16)a1.y, (_Float16)a1.z, (_Float16)a1.w };
    *(f16x8*)&Al[0][ar][ak] = ah;
  }
  __syncthreads();

  for (int t = 0; t < 64; ++t) {
    const int cur = t & 1;
    float4 na0, na1; f16x8 nb[4];
    if (t < 63) {
      const int k0 = (t + 1) * 32;
      na0 = *(const float4*)&X[(size_t)(mBase + ar) * D_ + k0 + ak];
      na1 = *(const float4*)&X[(size_t)(mBase + ar) * D_ + k0 + ak + 4];
      const _Float16* bp = Bb + (size_t)(t + 1) * PSTRIDE;
#pragma unroll
      for (int n = 0; n < 4; ++n) nb[n] = *(const f16x8*)&bp[(size_t)n * 512];
    }
    f16x8 af[4];
#pragma unroll
    for (int m = 0; m < 4; ++m) af[m] = *(const f16x8*)&Al[cur][m * 16 + fr_row][fr_k];
#pragma unroll
    for (int m = 0; m < 4; ++m)
#pragma unroll
      for (int n = 0; n < 4; ++n)
        acc[m][n] = __builtin_amdgcn_mfma_f32_16x16x32_f16(af[m], bf[n], acc[m][n], 0, 0, 0);
    if (t < 63) {
      f16x8 ah = { (_Float16)na0.x, (_Float16)na0.y, (_Float16)na0.z, (_Float16)na0.w,
                   (_Float16)na1.x, (_Float16)na1.y, (_Float16)na1.z, (_Float16)na1.w };
      *(f16x8*)&Al[cur ^ 1][ar][ak] = ah;
#pragma unroll
      for (int n = 0; n < 4; ++n) bf[n] = nb[n];
    }
    __syncthreads();
  }

  const int orow0 = mBase + (lane >> 4) * 4;
#pragma unroll
  for (int m = 0; m < 4; ++m) {
#pragma unroll
    for (int n = 0; n < 4; ++n) {
      int col = nBase + wave * 64 + n * 16 + (lane & 15);
#pragma unroll
      for (int i = 0; i < 4; ++i)
        H[(size_t)(orow0 + m * 16 + i) * F_ + col] = acc[m][n][i];
    }
  }
}

__global__ __launch_bounds__(256) void e_kernel(const float* __restrict__ H,
                                                const float* __restrict__ as,
                                                const float* __restrict__ ad,
                                                float* __restrict__ es,
                                                float* __restrict__ ed) {
  int row  = blockIdx.x * 4 + (threadIdx.x >> 6);
  int lane = threadIdx.x & 63;
  const float* h = H + (size_t)row * F_;
  float s = 0.f, d = 0.f;
#pragma unroll
  for (int p = 0; p < 2; ++p) {
    int col = p * 256 + lane * 4;
    float4 hv = *(const float4*)&h[col];
    float4 av = *(const float4*)&as[col];
    float4 dv = *(const float4*)&ad[col];
    s += hv.x * av.x + hv.y * av.y + hv.z * av.z + hv.w * av.w;
    d += hv.x * dv.x + hv.y * dv.y + hv.z * dv.z + hv.w * dv.w;
  }
  s = wave_reduce_sum(s);
  d = wave_reduce_sum(d);
  if (lane == 0) { es[row] = s; ed[row] = d; }
}

// ---------- kNN screen R12 (fallback path, validated) ----------
__global__ __launch_bounds__(256, 3) void knn_screen(const float* __restrict__ X,
                                                     int* __restrict__ cand8,
                                                     float* __restrict__ gapw) {
  __shared__ _Float16 T[2][256][40];
  __shared__ float sqA[256];

  const int bi  = blockIdx.x;
  const int xcd = bi & 7;
  const int kk  = bi >> 3;
  const int b   = ((kk >> 2) << 3) | xcd;
  const int i0  = (kk & 3) * 64;

  const int tid  = threadIdx.x;
  const int lane = tid & 63;
  const int wave = tid >> 6;
  const float* Xb = X + (size_t)b * N_ * D_;
  const int fr_row = lane & 15;
  const int fr_k   = (lane >> 4) * 8;
  const int srow = tid >> 3;
  const int skk  = (tid & 7) * 4;

  f32x4 acc[13] = {};
  float sqp[8] = {};

  {
    float4 v[8];
#pragma unroll
    for (int p = 0; p < 8; ++p) {
      int r = p * 32 + srow;
      v[p] = make_float4(0.f, 0.f, 0.f, 0.f);
      if (r < N_) v[p] = *(const float4*)&Xb[(size_t)r * D_ + skk];
    }
#pragma unroll
    for (int p = 0; p < 8; ++p) {
      int r = p * 32 + srow;
      sqp[p] += v[p].x * v[p].x + v[p].y * v[p].y + v[p].z * v[p].z + v[p].w * v[p].w;
      f16x4 h4 = { (_Float16)v[p].x, (_Float16)v[p].y, (_Float16)v[p].z, (_Float16)v[p].w };
      *(f16x4*)&T[0][r][skk] = h4;
    }
  }
  __syncthreads();

  for (int t = 0; t < 64; ++t) {
    const int cur = t & 1;
    float4 nv[8];
    if (t < 63) {
      const int k0 = (t + 1) * 32;
#pragma unroll
      for (int p = 0; p < 8; ++p) {
        int r = p * 32 + srow;
        nv[p] = make_float4(0.f, 0.f, 0.f, 0.f);
        if (r < N_) nv[p] = *(const float4*)&Xb[(size_t)r * D_ + k0 + skk];
      }
    }
    f16x8 a0 = *(const f16x8*)&T[cur][i0 + wave * 16 + fr_row][fr_k];
#pragma unroll
    for (int n = 0; n < 13; ++n) {
      f16x8 bfr = *(const f16x8*)&T[cur][n * 16 + fr_row][fr_k];
      acc[n] = __builtin_amdgcn_mfma_f32_16x16x32_f16(a0, bfr, acc[n], 0, 0, 0);
    }
    if (t < 63) {
#pragma unroll
      for (int p = 0; p < 8; ++p) {
        int r = p * 32 + srow;
        sqp[p] += nv[p].x * nv[p].x + nv[p].y * nv[p].y + nv[p].z * nv[p].z + nv[p].w * nv[p].w;
        f16x4 h4 = { (_Float16)nv[p].x, (_Float16)nv[p].y, (_Float16)nv[p].z, (_Float16)nv[p].w };
        *(f16x4*)&T[cur ^ 1][r][skk] = h4;
      }
    }
    __syncthreads();
  }

#pragma unroll
  for (int p = 0; p < 8; ++p) {
    float s = sqp[p];
    s += __shfl_xor(s, 1); s += __shfl_xor(s, 2); s += __shfl_xor(s, 4);
    if ((lane & 7) == 0) sqA[p * 32 + srow] = s;
  }
  __syncthreads();

  float sqv[13];
#pragma unroll
  for (int n = 0; n < 13; ++n) sqv[n] = sqA[n * 16 + (lane & 15)];
  const int g = lane >> 4;
#pragma unroll
  for (int i = 0; i < 4; ++i) {
    int row_loc = wave * 16 + g * 4 + i;
    float w13[13];
#pragma unroll
    for (int n = 0; n < 13; ++n) {
      int col = n * 16 + (lane & 15);
      w13[n] = (col < N_) ? (sqv[n] - 2.0f * acc[n][i]) : 1e30f;
    }
    int candv[CAND]; float mscv[CAND];
#pragma unroll
    for (int it = 0; it < CAND; ++it) {
      float mv = w13[0]; int mn = 0;
#pragma unroll
      for (int n = 1; n < 13; ++n)
        if (w13[n] < mv) { mv = w13[n]; mn = n; }
      int mcol = mn * 16 + (lane & 15);
#pragma unroll
      for (int off = 1; off <= 8; off <<= 1) {
        float ov = __shfl_xor(mv, off);
        int   oc = __shfl_xor(mcol, off);
        if (ov < mv || (ov == mv && oc < mcol)) { mv = ov; mcol = oc; }
      }
      mscv[it] = mv; candv[it] = mcol;
      int kn = mcol >> 4;
#pragma unroll
      for (int n = 0; n < 13; ++n)
        if (n == kn && (lane & 15) == (mcol & 15)) w13[n] = 1e30f;
    }
    int ig = i0 + row_loc;
    if ((lane & 15) == 0 && ig < N_) {
      size_t o = ((size_t)b * N_ + ig) * CAND;
#pragma unroll
      for (int c = 0; c < CAND; ++c) cand8[o + c] = candv[c];
      gapw[b * N_ + ig] = mscv[5] - mscv[4];
    }
  }
}

// ---------- kNN screen PAN: LDS-free, barrier-free, streams fp16 panels ----------
__global__ __launch_bounds__(256) void knn_screen_pan(const _Float16* __restrict__ Xh,
                                                      const float* __restrict__ sqg,
                                                      int* __restrict__ cand8,
                                                      float* __restrict__ gapw) {
  const int bi  = blockIdx.x;
  const int xcd = bi & 7;
  const int kk  = bi >> 3;
  const int b   = ((kk >> 2) << 3) | xcd;
  const int i0  = (kk & 3) * 64;

  const int tid  = threadIdx.x;
  const int lane = tid & 63;
  const int wave = tid >> 6;
  if (i0 + wave * 16 >= N_) return;   // wave-uniform; no barriers in this kernel

  const int fr_row = lane & 15;
  const int fr_k   = (lane >> 4) * 8;

  const _Float16* Pb = Xh + (size_t)b * 64 * PELEMS;
  const int aoff = (i0 + wave * 16 + fr_row) * 32 + fr_k;   // max row 207 < PROWS

  f32x4 acc[13] = {};
#pragma unroll 2
  for (int t = 0; t < 64; ++t) {
    const _Float16* P = Pb + (size_t)t * PELEMS;
    f16x8 a0 = *(const f16x8*)&P[aoff];
#pragma unroll
    for (int n = 0; n < 13; ++n) {
      f16x8 bfr = *(const f16x8*)&P[(n * 16 + fr_row) * 32 + fr_k];
      acc[n] = __builtin_amdgcn_mfma_f32_16x16x32_f16(a0, bfr, acc[n], 0, 0, 0);
    }
  }

  float sqv[13];
#pragma unroll
  for (int n = 0; n < 13; ++n) {
    int col = n * 16 + (lane & 15);
    sqv[n] = (col < N_) ? sqg[b * N_ + col] : 0.f;
  }
  const int g = lane >> 4;
#pragma unroll
  for (int i = 0; i < 4; ++i) {
    int row_loc = wave * 16 + g * 4 + i;
    float w13[13];
#pragma unroll
    for (int n = 0; n < 13; ++n) {
      int col = n * 16 + (lane & 15);
      w13[n] = (col < N_) ? (sqv[n] - 2.0f * acc[n][i]) : 1e30f;
    }
    int candv[CAND]; float mscv[CAND];
#pragma unroll
    for (int it = 0; it < CAND; ++it) {
      float mv = w13[0]; int mn = 0;
#pragma unroll
      for (int n = 1; n < 13; ++n)
        if (w13[n] < mv) { mv = w13[n]; mn = n; }
      int mcol = mn * 16 + (lane & 15);
#pragma unroll
      for (int off = 1; off <= 8; off <<= 1) {
        float ov = __shfl_xor(mv, off);
        int   oc = __shfl_xor(mcol, off);
        if (ov < mv || (ov == mv && oc < mcol)) { mv = ov; mcol = oc; }
      }
      mscv[it] = mv; candv[it] = mcol;
      int kn = mcol >> 4;
#pragma unroll
      for (int n = 0; n < 13; ++n)
        if (n == kn && (lane & 15) == (mcol & 15)) w13[n] = 1e30f;
    }
    int ig = i0 + row_loc;
    if ((lane & 15) == 0 && ig < N_) {
      size_t o = ((size_t)b * N_ + ig) * CAND;
#pragma unroll
      for (int c = 0; c < CAND; ++c) cand8[o + c] = candv[c];
      gapw[b * N_ + ig] = mscv[5] - mscv[4];
    }
  }
}

// ---------- kNN resolve: one wave per row; 3-tier (validated logic) ----------
__global__ __launch_bounds__(256) void knn_resolve(const float* __restrict__ X,
                                                   const int* __restrict__ cand8,
                                                   const float* __restrict__ gapw,
                                                   const float* __restrict__ es,
                                                   const float* __restrict__ ed,
                                                   int dual,
                                                   int* __restrict__ idx5,
                                                   float* __restrict__ alpha5) {
  const int gr   = blockIdx.x * 4 + (threadIdx.x >> 6);
  const int lane = threadIdx.x & 63;
  const int b    = gr / N_;
  const int ig   = gr - b * N_;
  const float* Xb = X + (size_t)b * N_ * D_;
  const float* xi = Xb + (size_t)ig * D_;

  int cand[CAND];
#pragma unroll
  for (int c = 0; c < CAND; ++c) cand[c] = cand8[(size_t)gr * CAND + c];
  float gap = gapw[gr];

  int ordj[5];
  if (gap > 0.75f) {
#pragma unroll
    for (int m5 = 0; m5 < 5; ++m5) ordj[m5] = cand[m5];
  } else {
    float4 xr[8];
#pragma unroll
    for (int q = 0; q < 8; ++q) xr[q] = *(const float4*)&xi[q * 256 + lane * 4];
    double s8[CAND];
#pragma unroll
    for (int c = 0; c < CAND; ++c) {
      const float* xj = Xb + (size_t)cand[c] * D_;
      double dsum = 0.0, sqc = 0.0;
#pragma unroll
      for (int q = 0; q < 8; ++q) {
        float4 u = *(const float4*)&xj[q * 256 + lane * 4];
        dsum += (double)xr[q].x * (double)u.x + (double)xr[q].y * (double)u.y
              + (double)xr[q].z * (double)u.z + (double)xr[q].w * (double)u.w;
        sqc  += (double)u.x * (double)u.x + (double)u.y * (double)u.y
              + (double)u.z * (double)u.z + (double)u.w * (double)u.w;
      }
      dsum = wave_reduce_sum_d(dsum);
      sqc  = wave_reduce_sum_d(sqc);
      s8[c] = sqc - 2.0 * dsum;
    }
    int rnk[CAND];
#pragma unroll
    for (int c = 0; c < CAND; ++c) {
      int r = 0;
#pragma unroll
      for (int c2 = 0; c2 < CAND; ++c2)
        if (c2 != c && (s8[c2] < s8[c] || (s8[c2] == s8[c] && cand[c2] < cand[c]))) r++;
      rnk[c] = r;
    }
    double g5 = 0.0, g6 = 0.0;
#pragma unroll
    for (int c = 0; c < CAND; ++c) {
      if (rnk[c] == 4) g5 = s8[c];
      if (rnk[c] == 5) g6 = s8[c];
    }
#pragma unroll
    for (int m5 = 0; m5 < 5; ++m5) {
      int oj = 0;
#pragma unroll
      for (int c = 0; c < CAND; ++c)
        if (rnk[c] == m5) oj = cand[c];
      ordj[m5] = oj;
    }
    if (!(g6 - g5 > 4e-3)) {
      float sqi_ex = np_sq_row(xi, lane);
      float sqc_ex[CAND];
#pragma unroll
      for (int c = 0; c < CAND; ++c)
        sqc_ex[c] = np_sq_row(Xb + (size_t)cand[c] * D_, lane);
      int grp8 = (lane >> 2) & 7;
      int l4 = lane & 3;
      int cj = cand[0];
#pragma unroll
      for (int c = 1; c < CAND; ++c)
        if (grp8 == c) cj = cand[c];
      const float* xjr = Xb + (size_t)cj * D_;
      float aacc = 0.f;
      for (int s5 = 0; s5 < 512; ++s5) {
        int d = s5 * 4 + l4;
        aacc = __fadd_rn(aacc, __fmul_rn(xi[d], xjr[d]));
      }
      float d2c[CAND];
#pragma unroll
      for (int c = 0; c < CAND; ++c) {
        float s0 = __shfl(aacc, c * 4 + 0);
        float s1 = __shfl(aacc, c * 4 + 1);
        float s2 = __shfl(aacc, c * 4 + 2);
        float s3 = __shfl(aacc, c * 4 + 3);
        float G  = __fadd_rn(__fadd_rn(s0, s1), __fadd_rn(s2, s3));
        float Sij = __fadd_rn(sqi_ex, sqc_ex[c]);
        d2c[c] = __fsub_rn(Sij, __fadd_rn(G, G));
      }
      int rnk3[CAND];
#pragma unroll
      for (int c = 0; c < CAND; ++c) {
        int r = 0;
#pragma unroll
        for (int c2 = 0; c2 < CAND; ++c2)
          if (c2 != c && (d2c[c2] < d2c[c] || (d2c[c2] == d2c[c] && cand[c2] < cand[c]))) r++;
        rnk3[c] = r;
      }
#pragma unroll
      for (int m5 = 0; m5 < 5; ++m5) {
        int oj = 0;
#pragma unroll
        for (int c = 0; c < CAND; ++c)
          if (rnk3[c] == m5) oj = cand[c];
        ordj[m5] = oj;
      }
    }
  }
  float ei = es[gr] + (dual ? es[ROWS + gr] : 0.f);
  float ev[5];
#pragma unroll
  for (int m5 = 0; m5 < 5; ++m5) {
    int jj = b * N_ + ordj[m5];
    float e = ei + ed[jj] + (dual ? ed[ROWS + jj] : 0.f);
    ev[m5] = e > 0.f ? e : 0.2f * e;
  }
  float mx = fmaxf(fmaxf(fmaxf(ev[0], ev[1]), fmaxf(ev[2], ev[3])), ev[4]);
  float p0 = expf(ev[0] - mx), p1 = expf(ev[1] - mx), p2 = expf(ev[2] - mx),
        p3 = expf(ev[3] - mx), p4 = expf(ev[4] - mx);
  float inv = 1.0f / (p0 + p1 + p2 + p3 + p4);
  if (lane == 0) {
    size_t o = (size_t)gr * 5;
    idx5[o + 0] = ordj[0]; alpha5[o + 0] = p0 * inv;
    idx5[o + 1] = ordj[1]; alpha5[o + 1] = p1 * inv;
    idx5[o + 2] = ordj[2]; alpha5[o + 2] = p2 * inv;
    idx5[o + 3] = ordj[3]; alpha5[o + 3] = p3 * inv;
    idx5[o + 4] = ordj[4]; alpha5[o + 4] = p4 * inv;
  }
}

// ---------- out[b,i,:] = elu( sum_c alpha_c * H[b, j_c, :] ) ----------
__global__ __launch_bounds__(128) void agg_kernel(const float* __restrict__ H,
                                                  const int* __restrict__ idx5,
                                                  const float* __restrict__ alpha5,
                                                  float* __restrict__ out) {
  int row = blockIdx.x;
  int b = row / N_;
  int t = threadIdx.x;
  size_t base5 = (size_t)row * 5;
  const float* Hb = H + (size_t)b * N_ * F_;
  float ax = 0.f, ay = 0.f, az = 0.f, aw = 0.f;
#pragma unroll
  for (int c = 0; c < 5; ++c) {
    int j   = idx5[base5 + c];
    float a = alpha5[base5 + c];
    float4 hv = *(const float4*)&Hb[(size_t)j * F_ + t * 4];
    ax += a * hv.x; ay += a * hv.y; az += a * hv.z; aw += a * hv.w;
  }
  float4 o;
  o.x = ax > 0.f ? ax : expf(ax) - 1.f;
  o.y = ay > 0.f ? ay : expf(ay) - 1.f;
  o.z = az > 0.f ? az : expf(az) - 1.f;
  o.w = aw > 0.f ? aw : expf(aw) - 1.f;
  *(float4*)&out[(size_t)row * F_ + t * 4] = o;
}

extern "C" void kernel_launch(void* const* d_in, const int* in_sizes, int n_in,
                              void* d_out, int out_size, void* d_ws, size_t ws_size,
                              hipStream_t stream) {
  const float* X    = (const float*)d_in[0];
  const float* W    = (const float*)d_in[1];
  const float* Asrc = (const float*)d_in[2];
  const float* Adst = (const float*)d_in[3];
  float* out = (float*)d_out;

  const size_t OFF_WT  = 0;                       // 2,097,152 (Wt2 k-panels)
  const size_t OFF_ES  = OFF_WT + 2097152;        // 2*ROWS*4 = 401,408
  const size_t OFF_ED  = OFF_ES + 401408;         // 2*ROWS*4
  const size_t OFF_IDX = OFF_ED + 401408;
  const size_t OFF_ALP = OFF_IDX + 1003520;
  const size_t OFF_C8  = OFF_ALP + 1003520;       // 50176*8*4
  const size_t OFF_GAP = OFF_C8 + 1605632;
  const size_t OFF_SQG = OFF_GAP + 200704;        // 50176*4
  const size_t OFF_H   = OFF_SQG + 200704;        // 102,760,448
  const size_t OFF_XH  = OFF_H + (size_t)ROWS * F_ * 4;
  const size_t XH_BYTES = (size_t)B_ * 64 * PELEMS * 2;   // 218,103,808
  const size_t NEED_A  = OFF_XH;
  const size_t NEED_B  = OFF_XH + XH_BYTES;
  if (ws_size < NEED_A) return;

  char* ws = (char*)d_ws;
  _Float16* Wt2 = (_Float16*)(ws + OFF_WT);
  float* es     = (float*)(ws + OFF_ES);
  float* ed     = (float*)(ws + OFF_ED);
  int*   idx5   = (int*)  (ws + OFF_IDX);
  float* alpha5 = (float*)(ws + OFF_ALP);
  int*   cand8  = (int*)  (ws + OFF_C8);
  float* gapw   = (float*)(ws + OFF_GAP);
  float* sqg    = (float*)(ws + OFF_SQG);
  float* H      = (float*)(ws + OFF_H);
  _Float16* Xh  = (_Float16*)(ws + OFF_XH);

  wtrans_kernel<<<dim3(32, 8), 256, 0, stream>>>(W, Wt2);
  if (ws_size >= NEED_B) {
    panelize_kernel<<<ROWS / 32, 256, 0, stream>>>(X, Xh, sqg);
    h_gemm_p<<<dim3(2, 784), 256, 0, stream>>>(Xh, Wt2, Asrc, Adst, H, es, ed);
    knn_screen_pan<<<1024, 256, 0, stream>>>(Xh, sqg, cand8, gapw);
    knn_resolve<<<ROWS / 4, 256, 0, stream>>>(X, cand8, gapw, es, ed, 1, idx5, alpha5);
  } else {
    h_gemm<<<dim3(2, 784), 256, 0, stream>>>(X, Wt2, H);
    e_kernel<<<ROWS / 4, 256, 0, stream>>>(H, Asrc, Adst, es, ed);
    knn_screen<<<1024, 256, 0, stream>>>(X, cand8, gapw);
    knn_resolve<<<ROWS / 4, 256, 0, stream>>>(X, cand8, gapw, es, ed, 0, idx5, alpha5);
  }
  agg_kernel<<<ROWS, 128, 0, stream>>>(H, idx5, alpha5, out);
}

// Round 19
// 634.274 us; speedup vs baseline: 1.5948x; 1.5948x over previous
//
#include <hip/hip_runtime.h>

#define B_  256
#define N_  196
#define D_  2048
#define F_  512
#define ROWS (B_*N_)   // 50176
#define CAND 8
#define PROWS 208
#define PELEMS (PROWS*32)   // 6656 fp16 per panel

typedef _Float16 f16x8 __attribute__((ext_vector_type(8)));
typedef _Float16 f16x4 __attribute__((ext_vector_type(4)));
typedef float    f32x4 __attribute__((ext_vector_type(4)));

static __device__ __forceinline__ float wave_reduce_sum(float v) {
#pragma unroll
  for (int off = 32; off > 0; off >>= 1) v += __shfl_xor(v, off);
  return v;
}

static __device__ __forceinline__ double wave_reduce_sum_d(double v) {
#pragma unroll
  for (int off = 32; off > 0; off >>= 1) v += __shfl_xor(v, off);
  return v;
}

// numpy pairwise-sum replica of sum(x*x) (R5-validated, bit-exact).
static __device__ __forceinline__ float np_chain16(const float* __restrict__ x, int h) {
  int base = (h >> 3) * 128 + (h & 7);
  float t0 = x[base];
  float r = __fmul_rn(t0, t0);
#pragma unroll
  for (int i = 1; i < 16; ++i) {
    float t = x[base + 8 * i];
    r = __fadd_rn(r, __fmul_rn(t, t));
  }
  return r;
}
static __device__ __forceinline__ float np_sq_row(const float* __restrict__ x, int lane) {
  float ra = np_chain16(x, lane);
  float rb = np_chain16(x, lane + 64);
#pragma unroll
  for (int off = 1; off <= 4; off <<= 1) {
    ra = __fadd_rn(ra, __shfl_xor(ra, off));
    rb = __fadd_rn(rb, __shfl_xor(rb, off));
  }
  float lf[16];
#pragma unroll
  for (int L = 0; L < 8; ++L) { lf[L] = __shfl(ra, L * 8); lf[8 + L] = __shfl(rb, L * 8); }
  float b8[8];
#pragma unroll
  for (int t = 0; t < 8; ++t) b8[t] = __fadd_rn(lf[2 * t], lf[2 * t + 1]);
  float c4[4];
#pragma unroll
  for (int t = 0; t < 4; ++t) c4[t] = __fadd_rn(b8[2 * t], b8[2 * t + 1]);
  return __fadd_rn(__fadd_rn(c4[0], c4[1]), __fadd_rn(c4[2], c4[3]));
}

// ---------- W [K][F] fp32  ->  Wt2 k-panels: [K/32][F][32] fp16 ----------
__global__ __launch_bounds__(256) void wtrans_kernel(const float* __restrict__ W,
                                                     _Float16* __restrict__ Wt2) {
  __shared__ float T[64][68];
  int k0 = blockIdx.x * 64;
  int f0 = blockIdx.y * 64;
  int tid = threadIdx.x;
  int c = tid & 63;
  int r4 = tid >> 6;
#pragma unroll
  for (int p = 0; p < 16; ++p) {
    int r = p * 4 + r4;
    T[r][c] = W[(size_t)(k0 + r) * F_ + f0 + c];
  }
  __syncthreads();
#pragma unroll
  for (int p = 0; p < 16; ++p) {
    int fr = p * 4 + r4;
    int kg = k0 + c;
    Wt2[(size_t)(kg >> 5) * F_ * 32 + (size_t)(f0 + fr) * 32 + (kg & 31)] = (_Float16)T[c][fr];
  }
}

// ---------- h_gemm_pan (R15/R17-validated) + fused e_src/e_dst ----------
__global__ __launch_bounds__(512, 2) void h_gemm_pan(const float* __restrict__ X,
                                                     const _Float16* __restrict__ Wt2,
                                                     const float* __restrict__ As,
                                                     const float* __restrict__ Ad,
                                                     float* __restrict__ H,
                                                     _Float16* __restrict__ Xh,
                                                     float* __restrict__ sqg,
                                                     float* __restrict__ es,
                                                     float* __restrict__ ed) {
  __shared__ _Float16 Al[2][64][40];
  __shared__ float eS[64][8];
  __shared__ float eD[64][8];
  const int mBase = blockIdx.x * 64;
  const int tid  = threadIdx.x;
  const int lane = tid & 63;
  const int wave = tid >> 6;           // 0..7, owns cols wave*64..+63
  const int fr_row = lane & 15;
  const int fr_k   = (lane >> 4) * 8;
  const int ar = tid >> 3;             // 0..63 (A staging row)
  const int ak = (tid & 7) * 4;        // 0,4,...,28 (A staging col)
  f32x4 acc[4][4] = {};
  float sqp = 0.f;

  const int grow = mBase + ar;
  const int bb = grow / N_;
  const int rl = grow - bb * N_;
  _Float16* pRow = Xh + (size_t)bb * 64 * PELEMS + (size_t)rl * 32 + ak;

  const _Float16* Bb = Wt2 + (size_t)(wave * 64 + fr_row) * 32 + fr_k;
  const size_t PSTRIDE = (size_t)F_ * 32;

  f16x8 bf[4];
#pragma unroll
  for (int n = 0; n < 4; ++n) bf[n] = *(const f16x8*)&Bb[(size_t)n * 512];

  {
    float4 a0 = *(const float4*)&X[(size_t)grow * D_ + ak];
    f16x4 ah = { (_Float16)a0.x, (_Float16)a0.y, (_Float16)a0.z, (_Float16)a0.w };
    *(f16x4*)&Al[0][ar][ak] = ah;
    sqp += a0.x * a0.x + a0.y * a0.y + a0.z * a0.z + a0.w * a0.w;
    *(f16x4*)pRow = ah;                 // panel 0
  }
  __syncthreads();

  for (int t = 0; t < 64; ++t) {
    const int cur = t & 1;
    float4 na; f16x8 nb[4];
    if (t < 63) {
      const int k0 = (t + 1) * 32;
      na = *(const float4*)&X[(size_t)grow * D_ + k0 + ak];
      const _Float16* bp = Bb + (size_t)(t + 1) * PSTRIDE;
#pragma unroll
      for (int n = 0; n < 4; ++n) nb[n] = *(const f16x8*)&bp[(size_t)n * 512];
    }
    f16x8 af[4];
#pragma unroll
    for (int m = 0; m < 4; ++m) af[m] = *(const f16x8*)&Al[cur][m * 16 + fr_row][fr_k];
#pragma unroll
    for (int m = 0; m < 4; ++m)
#pragma unroll
      for (int n = 0; n < 4; ++n)
        acc[m][n] = __builtin_amdgcn_mfma_f32_16x16x32_f16(af[m], bf[n], acc[m][n], 0, 0, 0);
    if (t < 63) {
      f16x4 nah = { (_Float16)na.x, (_Float16)na.y, (_Float16)na.z, (_Float16)na.w };
      *(f16x4*)&Al[cur ^ 1][ar][ak] = nah;
      sqp += na.x * na.x + na.y * na.y + na.z * na.z + na.w * na.w;
      *(f16x4*)(pRow + (size_t)(t + 1) * PELEMS) = nah;   // panel t+1
#pragma unroll
      for (int n = 0; n < 4; ++n) bf[n] = nb[n];
    }
    __syncthreads();
  }

  // approx row-norm: 8 staging lanes per row reduce
  {
    float s = sqp;
    s += __shfl_xor(s, 1); s += __shfl_xor(s, 2); s += __shfl_xor(s, 4);
    if ((lane & 7) == 0) sqg[grow] = s;
  }

  // ---- fused e_src/e_dst ----
  {
    float as_v[4], ad_v[4];
#pragma unroll
    for (int n = 0; n < 4; ++n) {
      int col = wave * 64 + n * 16 + (lane & 15);
      as_v[n] = As[col]; ad_v[n] = Ad[col];
    }
#pragma unroll
    for (int m = 0; m < 4; ++m) {
#pragma unroll
      for (int i = 0; i < 4; ++i) {
        float ps = 0.f, pd = 0.f;
#pragma unroll
        for (int n = 0; n < 4; ++n) {
          ps += acc[m][n][i] * as_v[n];
          pd += acc[m][n][i] * ad_v[n];
        }
#pragma unroll
        for (int off = 1; off <= 8; off <<= 1) {
          ps += __shfl_xor(ps, off);
          pd += __shfl_xor(pd, off);
        }
        if ((lane & 15) == 0) {
          int row_loc = (lane >> 4) * 4 + i + m * 16;
          eS[row_loc][wave] = ps;
          eD[row_loc][wave] = pd;
        }
      }
    }
  }
  __syncthreads();
  if (tid < 64) {
    float s = 0.f, d = 0.f;
#pragma unroll
    for (int w = 0; w < 8; ++w) { s += eS[tid][w]; d += eD[tid][w]; }
    es[mBase + tid] = s;
    ed[mBase + tid] = d;
  }

  const int orow0 = mBase + (lane >> 4) * 4;
#pragma unroll
  for (int m = 0; m < 4; ++m) {
#pragma unroll
    for (int n = 0; n < 4; ++n) {
      int col = wave * 64 + n * 16 + (lane & 15);
#pragma unroll
      for (int i = 0; i < 4; ++i)
        H[(size_t)(orow0 + m * 16 + i) * F_ + col] = acc[m][n][i];
    }
  }
}

// ---------- fallback: h_gemm R12 + e_kernel (validated) ----------
__global__ __launch_bounds__(256, 3) void h_gemm(const float* __restrict__ X,
                                                 const _Float16* __restrict__ Wt2,
                                                 float* __restrict__ H) {
  __shared__ _Float16 Al[2][64][40];
  const int mBase = blockIdx.y * 64;
  const int nBase = blockIdx.x * 256;
  const int tid  = threadIdx.x;
  const int lane = tid & 63;
  const int wave = tid >> 6;
  const int fr_row = lane & 15;
  const int fr_k   = (lane >> 4) * 8;
  const int ar = tid >> 2;
  const int ak = (tid & 3) * 8;
  f32x4 acc[4][4] = {};

  const _Float16* Bb = Wt2 + (size_t)(nBase + wave * 64 + fr_row) * 32 + fr_k;
  const size_t PSTRIDE = (size_t)F_ * 32;

  f16x8 bf[4];
#pragma unroll
  for (int n = 0; n < 4; ++n) bf[n] = *(const f16x8*)&Bb[(size_t)n * 512];

  {
    float4 a0 = *(const float4*)&X[(size_t)(mBase + ar) * D_ + ak];
    float4 a1 = *(const float4*)&X[(size_t)(mBase + ar) * D_ + ak + 4];
    f16x8 ah = { (_Float16)a0.x, (_Float16)a0.y, (_Float16)a0.z, (_Float16)a0.w,
                 (_Float16)a1.x, (_Float16)a1.y, (_Float16)a1.z, (_Float16)a1.w };
    *(f16x8*)&Al[0][ar][ak] = ah;
  }
  __syncthreads();

  for (int t = 0; t < 64; ++t) {
    const int cur = t & 1;
    float4 na0, na1; f16x8 nb[4];
    if (t < 63) {
      const int k0 = (t + 1) * 32;
      na0 = *(const float4*)&X[(size_t)(mBase + ar) * D_ + k0 + ak];
      na1 = *(const float4*)&X[(size_t)(mBase + ar) * D_ + k0 + ak + 4];
      const _Float16* bp = Bb + (size_t)(t + 1) * PSTRIDE;
#pragma unroll
      for (int n = 0; n < 4; ++n) nb[n] = *(const f16x8*)&bp[(size_t)n * 512];
    }
    f16x8 af[4];
#pragma unroll
    for (int m = 0; m < 4; ++m) af[m] = *(const f16x8*)&Al[cur][m * 16 + fr_row][fr_k];
#pragma unroll
    for (int m = 0; m < 4; ++m)
#pragma unroll
      for (int n = 0; n < 4; ++n)
        acc[m][n] = __builtin_amdgcn_mfma_f32_16x16x32_f16(af[m], bf[n], acc[m][n], 0, 0, 0);
    if (t < 63) {
      f16x8 ah = { (_Float16)na0.x, (_Float16)na0.y, (_Float16)na0.z, (_Float16)na0.w,
                   (_Float16)na1.x, (_Float16)na1.y, (_Float16)na1.z, (_Float16)na1.w };
      *(f16x8*)&Al[cur ^ 1][ar][ak] = ah;
#pragma unroll
      for (int n = 0; n < 4; ++n) bf[n] = nb[n];
    }
    __syncthreads();
  }

  const int orow0 = mBase + (lane >> 4) * 4;
#pragma unroll
  for (int m = 0; m < 4; ++m) {
#pragma unroll
    for (int n = 0; n < 4; ++n) {
      int col = nBase + wave * 64 + n * 16 + (lane & 15);
#pragma unroll
      for (int i = 0; i < 4; ++i)
        H[(size_t)(orow0 + m * 16 + i) * F_ + col] = acc[m][n][i];
    }
  }
}

__global__ __launch_bounds__(256) void e_kernel(const float* __restrict__ H,
                                                const float* __restrict__ as,
                                                const float* __restrict__ ad,
                                                float* __restrict__ es,
                                                float* __restrict__ ed) {
  int row  = blockIdx.x * 4 + (threadIdx.x >> 6);
  int lane = threadIdx.x & 63;
  const float* h = H + (size_t)row * F_;
  float s = 0.f, d = 0.f;
#pragma unroll
  for (int p = 0; p < 2; ++p) {
    int col = p * 256 + lane * 4;
    float4 hv = *(const float4*)&h[col];
    float4 av = *(const float4*)&as[col];
    float4 dv = *(const float4*)&ad[col];
    s += hv.x * av.x + hv.y * av.y + hv.z * av.z + hv.w * av.w;
    d += hv.x * dv.x + hv.y * dv.y + hv.z * dv.z + hv.w * dv.w;
  }
  s = wave_reduce_sum(s);
  d = wave_reduce_sum(d);
  if (lane == 0) { es[row] = s; ed[row] = d; }
}

// ---------- kNN screen R12 (fallback path, validated) ----------
__global__ __launch_bounds__(256, 3) void knn_screen(const float* __restrict__ X,
                                                     int* __restrict__ cand8,
                                                     float* __restrict__ gapw) {
  __shared__ _Float16 T[2][256][40];
  __shared__ float sqA[256];

  const int bi  = blockIdx.x;
  const int xcd = bi & 7;
  const int kk  = bi >> 3;
  const int b   = ((kk >> 2) << 3) | xcd;
  const int i0  = (kk & 3) * 64;

  const int tid  = threadIdx.x;
  const int lane = tid & 63;
  const int wave = tid >> 6;
  const float* Xb = X + (size_t)b * N_ * D_;
  const int fr_row = lane & 15;
  const int fr_k   = (lane >> 4) * 8;
  const int srow = tid >> 3;
  const int skk  = (tid & 7) * 4;

  f32x4 acc[13] = {};
  float sqp[8] = {};

  {
    float4 v[8];
#pragma unroll
    for (int p = 0; p < 8; ++p) {
      int r = p * 32 + srow;
      v[p] = make_float4(0.f, 0.f, 0.f, 0.f);
      if (r < N_) v[p] = *(const float4*)&Xb[(size_t)r * D_ + skk];
    }
#pragma unroll
    for (int p = 0; p < 8; ++p) {
      int r = p * 32 + srow;
      sqp[p] += v[p].x * v[p].x + v[p].y * v[p].y + v[p].z * v[p].z + v[p].w * v[p].w;
      f16x4 h4 = { (_Float16)v[p].x, (_Float16)v[p].y, (_Float16)v[p].z, (_Float16)v[p].w };
      *(f16x4*)&T[0][r][skk] = h4;
    }
  }
  __syncthreads();

  for (int t = 0; t < 64; ++t) {
    const int cur = t & 1;
    float4 nv[8];
    if (t < 63) {
      const int k0 = (t + 1) * 32;
#pragma unroll
      for (int p = 0; p < 8; ++p) {
        int r = p * 32 + srow;
        nv[p] = make_float4(0.f, 0.f, 0.f, 0.f);
        if (r < N_) nv[p] = *(const float4*)&Xb[(size_t)r * D_ + k0 + skk];
      }
    }
    f16x8 a0 = *(const f16x8*)&T[cur][i0 + wave * 16 + fr_row][fr_k];
#pragma unroll
    for (int n = 0; n < 13; ++n) {
      f16x8 bfr = *(const f16x8*)&T[cur][n * 16 + fr_row][fr_k];
      acc[n] = __builtin_amdgcn_mfma_f32_16x16x32_f16(a0, bfr, acc[n], 0, 0, 0);
    }
    if (t < 63) {
#pragma unroll
      for (int p = 0; p < 8; ++p) {
        int r = p * 32 + srow;
        sqp[p] += nv[p].x * nv[p].x + nv[p].y * nv[p].y + nv[p].z * nv[p].z + nv[p].w * nv[p].w;
        f16x4 h4 = { (_Float16)nv[p].x, (_Float16)nv[p].y, (_Float16)nv[p].z, (_Float16)nv[p].w };
        *(f16x4*)&T[cur ^ 1][r][skk] = h4;
      }
    }
    __syncthreads();
  }

#pragma unroll
  for (int p = 0; p < 8; ++p) {
    float s = sqp[p];
    s += __shfl_xor(s, 1); s += __shfl_xor(s, 2); s += __shfl_xor(s, 4);
    if ((lane & 7) == 0) sqA[p * 32 + srow] = s;
  }
  __syncthreads();

  float sqv[13];
#pragma unroll
  for (int n = 0; n < 13; ++n) sqv[n] = sqA[n * 16 + (lane & 15)];
  const int g = lane >> 4;
#pragma unroll
  for (int i = 0; i < 4; ++i) {
    int row_loc = wave * 16 + g * 4 + i;
    float w13[13];
#pragma unroll
    for (int n = 0; n < 13; ++n) {
      int col = n * 16 + (lane & 15);
      w13[n] = (col < N_) ? (sqv[n] - 2.0f * acc[n][i]) : 1e30f;
    }
    int candv[CAND]; float mscv[CAND];
#pragma unroll
    for (int it = 0; it < CAND; ++it) {
      float mv = w13[0]; int mn = 0;
#pragma unroll
      for (int n = 1; n < 13; ++n)
        if (w13[n] < mv) { mv = w13[n]; mn = n; }
      int mcol = mn * 16 + (lane & 15);
#pragma unroll
      for (int off = 1; off <= 8; off <<= 1) {
        float ov = __shfl_xor(mv, off);
        int   oc = __shfl_xor(mcol, off);
        if (ov < mv || (ov == mv && oc < mcol)) { mv = ov; mcol = oc; }
      }
      mscv[it] = mv; candv[it] = mcol;
      int kn = mcol >> 4;
#pragma unroll
      for (int n = 0; n < 13; ++n)
        if (n == kn && (lane & 15) == (mcol & 15)) w13[n] = 1e30f;
    }
    int ig = i0 + row_loc;
    if ((lane & 15) == 0 && ig < N_) {
      size_t o = ((size_t)b * N_ + ig) * CAND;
#pragma unroll
      for (int c = 0; c < CAND; ++c) cand8[o + c] = candv[c];
      gapw[b * N_ + ig] = mscv[5] - mscv[4];
    }
  }
}

// ---------- kNN screen PAN: LDS-free, barrier-free, streams fp16 panels ----------
__global__ __launch_bounds__(256) void knn_screen_pan(const _Float16* __restrict__ Xh,
                                                      const float* __restrict__ sqg,
                                                      int* __restrict__ cand8,
                                                      float* __restrict__ gapw) {
  const int bi  = blockIdx.x;
  const int xcd = bi & 7;
  const int kk  = bi >> 3;
  const int b   = ((kk >> 2) << 3) | xcd;
  const int i0  = (kk & 3) * 64;

  const int tid  = threadIdx.x;
  const int lane = tid & 63;
  const int wave = tid >> 6;
  if (i0 + wave * 16 >= N_) return;   // wave-uniform; no barriers in this kernel

  const int fr_row = lane & 15;
  const int fr_k   = (lane >> 4) * 8;

  const _Float16* Pb = Xh + (size_t)b * 64 * PELEMS;
  const int aoff = (i0 + wave * 16 + fr_row) * 32 + fr_k;   // max row 207 < PROWS

  f32x4 acc[13] = {};
#pragma unroll 2
  for (int t = 0; t < 64; ++t) {
    const _Float16* P = Pb + (size_t)t * PELEMS;
    f16x8 a0 = *(const f16x8*)&P[aoff];
#pragma unroll
    for (int n = 0; n < 13; ++n) {
      f16x8 bfr = *(const f16x8*)&P[(n * 16 + fr_row) * 32 + fr_k];
      acc[n] = __builtin_amdgcn_mfma_f32_16x16x32_f16(a0, bfr, acc[n], 0, 0, 0);
    }
  }

  float sqv[13];
#pragma unroll
  for (int n = 0; n < 13; ++n) {
    int col = n * 16 + (lane & 15);
    sqv[n] = (col < N_) ? sqg[b * N_ + col] : 0.f;
  }
  const int g = lane >> 4;
#pragma unroll
  for (int i = 0; i < 4; ++i) {
    int row_loc = wave * 16 + g * 4 + i;
    float w13[13];
#pragma unroll
    for (int n = 0; n < 13; ++n) {
      int col = n * 16 + (lane & 15);
      w13[n] = (col < N_) ? (sqv[n] - 2.0f * acc[n][i]) : 1e30f;
    }
    int candv[CAND]; float mscv[CAND];
#pragma unroll
    for (int it = 0; it < CAND; ++it) {
      float mv = w13[0]; int mn = 0;
#pragma unroll
      for (int n = 1; n < 13; ++n)
        if (w13[n] < mv) { mv = w13[n]; mn = n; }
      int mcol = mn * 16 + (lane & 15);
#pragma unroll
      for (int off = 1; off <= 8; off <<= 1) {
        float ov = __shfl_xor(mv, off);
        int   oc = __shfl_xor(mcol, off);
        if (ov < mv || (ov == mv && oc < mcol)) { mv = ov; mcol = oc; }
      }
      mscv[it] = mv; candv[it] = mcol;
      int kn = mcol >> 4;
#pragma unroll
      for (int n = 0; n < 13; ++n)
        if (n == kn && (lane & 15) == (mcol & 15)) w13[n] = 1e30f;
    }
    int ig = i0 + row_loc;
    if ((lane & 15) == 0 && ig < N_) {
      size_t o = ((size_t)b * N_ + ig) * CAND;
#pragma unroll
      for (int c = 0; c < CAND; ++c) cand8[o + c] = candv[c];
      gapw[b * N_ + ig] = mscv[5] - mscv[4];
    }
  }
}

// ---------- kNN resolve + FUSED agg: one wave per row; 3-tier; writes out directly ----------
__global__ __launch_bounds__(256) void knn_resolve(const float* __restrict__ X,
                                                   const float* __restrict__ H,
                                                   const int* __restrict__ cand8,
                                                   const float* __restrict__ gapw,
                                                   const float* __restrict__ es,
                                                   const float* __restrict__ ed,
                                                   float* __restrict__ out) {
  const int gr   = blockIdx.x * 4 + (threadIdx.x >> 6);
  const int lane = threadIdx.x & 63;
  const int b    = gr / N_;
  const int ig   = gr - b * N_;
  const float* Xb = X + (size_t)b * N_ * D_;
  const float* xi = Xb + (size_t)ig * D_;

  int cand[CAND];
#pragma unroll
  for (int c = 0; c < CAND; ++c) cand[c] = cand8[(size_t)gr * CAND + c];
  float gap = gapw[gr];

  int ordj[5];
  if (gap > 0.75f) {
#pragma unroll
    for (int m5 = 0; m5 < 5; ++m5) ordj[m5] = cand[m5];
  } else {
    float4 xr[8];
#pragma unroll
    for (int q = 0; q < 8; ++q) xr[q] = *(const float4*)&xi[q * 256 + lane * 4];
    double s8[CAND];
#pragma unroll
    for (int c = 0; c < CAND; ++c) {
      const float* xj = Xb + (size_t)cand[c] * D_;
      double dsum = 0.0, sqc = 0.0;
#pragma unroll
      for (int q = 0; q < 8; ++q) {
        float4 u = *(const float4*)&xj[q * 256 + lane * 4];
        dsum += (double)xr[q].x * (double)u.x + (double)xr[q].y * (double)u.y
              + (double)xr[q].z * (double)u.z + (double)xr[q].w * (double)u.w;
        sqc  += (double)u.x * (double)u.x + (double)u.y * (double)u.y
              + (double)u.z * (double)u.z + (double)u.w * (double)u.w;
      }
      dsum = wave_reduce_sum_d(dsum);
      sqc  = wave_reduce_sum_d(sqc);
      s8[c] = sqc - 2.0 * dsum;
    }
    int rnk[CAND];
#pragma unroll
    for (int c = 0; c < CAND; ++c) {
      int r = 0;
#pragma unroll
      for (int c2 = 0; c2 < CAND; ++c2)
        if (c2 != c && (s8[c2] < s8[c] || (s8[c2] == s8[c] && cand[c2] < cand[c]))) r++;
      rnk[c] = r;
    }
    double g5 = 0.0, g6 = 0.0;
#pragma unroll
    for (int c = 0; c < CAND; ++c) {
      if (rnk[c] == 4) g5 = s8[c];
      if (rnk[c] == 5) g6 = s8[c];
    }
#pragma unroll
    for (int m5 = 0; m5 < 5; ++m5) {
      int oj = 0;
#pragma unroll
      for (int c = 0; c < CAND; ++c)
        if (rnk[c] == m5) oj = cand[c];
      ordj[m5] = oj;
    }
    if (!(g6 - g5 > 4e-3)) {
      float sqi_ex = np_sq_row(xi, lane);
      float sqc_ex[CAND];
#pragma unroll
      for (int c = 0; c < CAND; ++c)
        sqc_ex[c] = np_sq_row(Xb + (size_t)cand[c] * D_, lane);
      int grp8 = (lane >> 2) & 7;
      int l4 = lane & 3;
      int cj = cand[0];
#pragma unroll
      for (int c = 1; c < CAND; ++c)
        if (grp8 == c) cj = cand[c];
      const float* xjr = Xb + (size_t)cj * D_;
      float aacc = 0.f;
      for (int s5 = 0; s5 < 512; ++s5) {
        int d = s5 * 4 + l4;
        aacc = __fadd_rn(aacc, __fmul_rn(xi[d], xjr[d]));
      }
      float d2c[CAND];
#pragma unroll
      for (int c = 0; c < CAND; ++c) {
        float s0 = __shfl(aacc, c * 4 + 0);
        float s1 = __shfl(aacc, c * 4 + 1);
        float s2 = __shfl(aacc, c * 4 + 2);
        float s3 = __shfl(aacc, c * 4 + 3);
        float G  = __fadd_rn(__fadd_rn(s0, s1), __fadd_rn(s2, s3));
        float Sij = __fadd_rn(sqi_ex, sqc_ex[c]);
        d2c[c] = __fsub_rn(Sij, __fadd_rn(G, G));
      }
      int rnk3[CAND];
#pragma unroll
      for (int c = 0; c < CAND; ++c) {
        int r = 0;
#pragma unroll
        for (int c2 = 0; c2 < CAND; ++c2)
          if (c2 != c && (d2c[c2] < d2c[c] || (d2c[c2] == d2c[c] && cand[c2] < cand[c]))) r++;
        rnk3[c] = r;
      }
#pragma unroll
      for (int m5 = 0; m5 < 5; ++m5) {
        int oj = 0;
#pragma unroll
        for (int c = 0; c < CAND; ++c)
          if (rnk3[c] == m5) oj = cand[c];
        ordj[m5] = oj;
      }
    }
  }
  // softmax over leaky_relu(e_src[i]+e_dst[j]) of the 5 neighbors
  float ei = es[gr];
  float ev[5];
#pragma unroll
  for (int m5 = 0; m5 < 5; ++m5) {
    float e = ei + ed[b * N_ + ordj[m5]];
    ev[m5] = e > 0.f ? e : 0.2f * e;
  }
  float mx = fmaxf(fmaxf(fmaxf(ev[0], ev[1]), fmaxf(ev[2], ev[3])), ev[4]);
  float p0 = expf(ev[0] - mx), p1 = expf(ev[1] - mx), p2 = expf(ev[2] - mx),
        p3 = expf(ev[3] - mx), p4 = expf(ev[4] - mx);
  float inv = 1.0f / (p0 + p1 + p2 + p3 + p4);
  float al[5] = { p0 * inv, p1 * inv, p2 * inv, p3 * inv, p4 * inv };

  // ---- fused aggregation: lane owns 8 consecutive output floats ----
  const float* Hb = H + (size_t)b * N_ * F_;
  float a0x = 0.f, a0y = 0.f, a0z = 0.f, a0w = 0.f;
  float a1x = 0.f, a1y = 0.f, a1z = 0.f, a1w = 0.f;
#pragma unroll
  for (int c = 0; c < 5; ++c) {
    const float* hr = Hb + (size_t)ordj[c] * F_ + lane * 8;
    float4 h0 = *(const float4*)hr;
    float4 h1 = *(const float4*)(hr + 4);
    float a = al[c];
    a0x += a * h0.x; a0y += a * h0.y; a0z += a * h0.z; a0w += a * h0.w;
    a1x += a * h1.x; a1y += a * h1.y; a1z += a * h1.z; a1w += a * h1.w;
  }
  float4 o0, o1;
  o0.x = a0x > 0.f ? a0x : expf(a0x) - 1.f;
  o0.y = a0y > 0.f ? a0y : expf(a0y) - 1.f;
  o0.z = a0z > 0.f ? a0z : expf(a0z) - 1.f;
  o0.w = a0w > 0.f ? a0w : expf(a0w) - 1.f;
  o1.x = a1x > 0.f ? a1x : expf(a1x) - 1.f;
  o1.y = a1y > 0.f ? a1y : expf(a1y) - 1.f;
  o1.z = a1z > 0.f ? a1z : expf(a1z) - 1.f;
  o1.w = a1w > 0.f ? a1w : expf(a1w) - 1.f;
  float* op = out + (size_t)gr * F_ + lane * 8;
  *(float4*)op = o0;
  *(float4*)(op + 4) = o1;
}

extern "C" void kernel_launch(void* const* d_in, const int* in_sizes, int n_in,
                              void* d_out, int out_size, void* d_ws, size_t ws_size,
                              hipStream_t stream) {
  const float* X    = (const float*)d_in[0];
  const float* W    = (const float*)d_in[1];
  const float* Asrc = (const float*)d_in[2];
  const float* Adst = (const float*)d_in[3];
  float* out = (float*)d_out;

  const size_t OFF_WT  = 0;                       // 2,097,152 (Wt2 k-panels)
  const size_t OFF_ES  = OFF_WT + 2097152;
  const size_t OFF_ED  = OFF_ES + 200704;
  const size_t OFF_C8  = OFF_ED + 200704;         // 50176*8*4
  const size_t OFF_GAP = OFF_C8 + 1605632;
  const size_t OFF_SQG = OFF_GAP + 200704;        // 50176*4
  const size_t OFF_H   = OFF_SQG + 200704;        // 102,760,448
  const size_t OFF_XH  = OFF_H + (size_t)ROWS * F_ * 4;
  const size_t XH_BYTES = (size_t)B_ * 64 * PELEMS * 2;   // 218,103,808
  const size_t NEED_A  = OFF_XH;
  const size_t NEED_B  = OFF_XH + XH_BYTES;
  if (ws_size < NEED_A) return;

  char* ws = (char*)d_ws;
  _Float16* Wt2 = (_Float16*)(ws + OFF_WT);
  float* es     = (float*)(ws + OFF_ES);
  float* ed     = (float*)(ws + OFF_ED);
  int*   cand8  = (int*)  (ws + OFF_C8);
  float* gapw   = (float*)(ws + OFF_GAP);
  float* sqg    = (float*)(ws + OFF_SQG);
  float* H      = (float*)(ws + OFF_H);
  _Float16* Xh  = (_Float16*)(ws + OFF_XH);

  wtrans_kernel<<<dim3(32, 8), 256, 0, stream>>>(W, Wt2);
  if (ws_size >= NEED_B) {
    h_gemm_pan<<<784, 512, 0, stream>>>(X, Wt2, Asrc, Adst, H, Xh, sqg, es, ed);
    knn_screen_pan<<<1024, 256, 0, stream>>>(Xh, sqg, cand8, gapw);
  } else {
    h_gemm<<<dim3(2, 784), 256, 0, stream>>>(X, Wt2, H);
    e_kernel<<<ROWS / 4, 256, 0, stream>>>(H, Asrc, Adst, es, ed);
    knn_screen<<<1024, 256, 0, stream>>>(X, cand8, gapw);
  }
  knn_resolve<<<ROWS / 4, 256, 0, stream>>>(X, H, cand8, gapw, es, ed, out);
}

// Round 20
// 621.494 us; speedup vs baseline: 1.6275x; 1.0206x over previous
//
#include <hip/hip_runtime.h>

#define B_  256
#define N_  196
#define D_  2048
#define F_  512
#define ROWS (B_*N_)   // 50176
#define CAND 8
#define PROWS 208
#define PELEMS (PROWS*32)   // 6656 fp16 per panel

typedef _Float16 f16x8 __attribute__((ext_vector_type(8)));
typedef _Float16 f16x4 __attribute__((ext_vector_type(4)));
typedef float    f32x4 __attribute__((ext_vector_type(4)));

static __device__ __forceinline__ float wave_reduce_sum(float v) {
#pragma unroll
  for (int off = 32; off > 0; off >>= 1) v += __shfl_xor(v, off);
  return v;
}

static __device__ __forceinline__ double wave_reduce_sum_d(double v) {
#pragma unroll
  for (int off = 32; off > 0; off >>= 1) v += __shfl_xor(v, off);
  return v;
}

// numpy pairwise-sum replica of sum(x*x) (R5-validated, bit-exact).
static __device__ __forceinline__ float np_chain16(const float* __restrict__ x, int h) {
  int base = (h >> 3) * 128 + (h & 7);
  float t0 = x[base];
  float r = __fmul_rn(t0, t0);
#pragma unroll
  for (int i = 1; i < 16; ++i) {
    float t = x[base + 8 * i];
    r = __fadd_rn(r, __fmul_rn(t, t));
  }
  return r;
}
static __device__ __forceinline__ float np_sq_row(const float* __restrict__ x, int lane) {
  float ra = np_chain16(x, lane);
  float rb = np_chain16(x, lane + 64);
#pragma unroll
  for (int off = 1; off <= 4; off <<= 1) {
    ra = __fadd_rn(ra, __shfl_xor(ra, off));
    rb = __fadd_rn(rb, __shfl_xor(rb, off));
  }
  float lf[16];
#pragma unroll
  for (int L = 0; L < 8; ++L) { lf[L] = __shfl(ra, L * 8); lf[8 + L] = __shfl(rb, L * 8); }
  float b8[8];
#pragma unroll
  for (int t = 0; t < 8; ++t) b8[t] = __fadd_rn(lf[2 * t], lf[2 * t + 1]);
  float c4[4];
#pragma unroll
  for (int t = 0; t < 4; ++t) c4[t] = __fadd_rn(b8[2 * t], b8[2 * t + 1]);
  return __fadd_rn(__fadd_rn(c4[0], c4[1]), __fadd_rn(c4[2], c4[3]));
}

// ---------- W [K][F] fp32  ->  Wt2 k-panels: [K/32][F][32] fp16 ----------
__global__ __launch_bounds__(256) void wtrans_kernel(const float* __restrict__ W,
                                                     _Float16* __restrict__ Wt2) {
  __shared__ float T[64][68];
  int k0 = blockIdx.x * 64;
  int f0 = blockIdx.y * 64;
  int tid = threadIdx.x;
  int c = tid & 63;
  int r4 = tid >> 6;
#pragma unroll
  for (int p = 0; p < 16; ++p) {
    int r = p * 4 + r4;
    T[r][c] = W[(size_t)(k0 + r) * F_ + f0 + c];
  }
  __syncthreads();
#pragma unroll
  for (int p = 0; p < 16; ++p) {
    int fr = p * 4 + r4;
    int kg = k0 + c;
    Wt2[(size_t)(kg >> 5) * F_ * 32 + (size_t)(f0 + fr) * 32 + (kg & 31)] = (_Float16)T[c][fr];
  }
}

// ---------- h_gemm_pan (R15/R17-validated) + fused e_src/e_dst ----------
__global__ __launch_bounds__(512, 2) void h_gemm_pan(const float* __restrict__ X,
                                                     const _Float16* __restrict__ Wt2,
                                                     const float* __restrict__ As,
                                                     const float* __restrict__ Ad,
                                                     float* __restrict__ H,
                                                     _Float16* __restrict__ Xh,
                                                     float* __restrict__ sqg,
                                                     float* __restrict__ es,
                                                     float* __restrict__ ed) {
  __shared__ _Float16 Al[2][64][40];
  __shared__ float eS[64][8];
  __shared__ float eD[64][8];
  const int mBase = blockIdx.x * 64;
  const int tid  = threadIdx.x;
  const int lane = tid & 63;
  const int wave = tid >> 6;           // 0..7, owns cols wave*64..+63
  const int fr_row = lane & 15;
  const int fr_k   = (lane >> 4) * 8;
  const int ar = tid >> 3;             // 0..63 (A staging row)
  const int ak = (tid & 7) * 4;        // 0,4,...,28 (A staging col)
  f32x4 acc[4][4] = {};
  float sqp = 0.f;

  const int grow = mBase + ar;
  const int bb = grow / N_;
  const int rl = grow - bb * N_;
  _Float16* pRow = Xh + (size_t)bb * 64 * PELEMS + (size_t)rl * 32 + ak;

  const _Float16* Bb = Wt2 + (size_t)(wave * 64 + fr_row) * 32 + fr_k;
  const size_t PSTRIDE = (size_t)F_ * 32;

  f16x8 bf[4];
#pragma unroll
  for (int n = 0; n < 4; ++n) bf[n] = *(const f16x8*)&Bb[(size_t)n * 512];

  {
    float4 a0 = *(const float4*)&X[(size_t)grow * D_ + ak];
    f16x4 ah = { (_Float16)a0.x, (_Float16)a0.y, (_Float16)a0.z, (_Float16)a0.w };
    *(f16x4*)&Al[0][ar][ak] = ah;
    sqp += a0.x * a0.x + a0.y * a0.y + a0.z * a0.z + a0.w * a0.w;
    *(f16x4*)pRow = ah;                 // panel 0
  }
  __syncthreads();

  for (int t = 0; t < 64; ++t) {
    const int cur = t & 1;
    float4 na; f16x8 nb[4];
    if (t < 63) {
      const int k0 = (t + 1) * 32;
      na = *(const float4*)&X[(size_t)grow * D_ + k0 + ak];
      const _Float16* bp = Bb + (size_t)(t + 1) * PSTRIDE;
#pragma unroll
      for (int n = 0; n < 4; ++n) nb[n] = *(const f16x8*)&bp[(size_t)n * 512];
    }
    f16x8 af[4];
#pragma unroll
    for (int m = 0; m < 4; ++m) af[m] = *(const f16x8*)&Al[cur][m * 16 + fr_row][fr_k];
#pragma unroll
    for (int m = 0; m < 4; ++m)
#pragma unroll
      for (int n = 0; n < 4; ++n)
        acc[m][n] = __builtin_amdgcn_mfma_f32_16x16x32_f16(af[m], bf[n], acc[m][n], 0, 0, 0);
    if (t < 63) {
      f16x4 nah = { (_Float16)na.x, (_Float16)na.y, (_Float16)na.z, (_Float16)na.w };
      *(f16x4*)&Al[cur ^ 1][ar][ak] = nah;
      sqp += na.x * na.x + na.y * na.y + na.z * na.z + na.w * na.w;
      *(f16x4*)(pRow + (size_t)(t + 1) * PELEMS) = nah;   // panel t+1
#pragma unroll
      for (int n = 0; n < 4; ++n) bf[n] = nb[n];
    }
    __syncthreads();
  }

  // approx row-norm: 8 staging lanes per row reduce
  {
    float s = sqp;
    s += __shfl_xor(s, 1); s += __shfl_xor(s, 2); s += __shfl_xor(s, 4);
    if ((lane & 7) == 0) sqg[grow] = s;
  }

  // ---- fused e_src/e_dst ----
  {
    float as_v[4], ad_v[4];
#pragma unroll
    for (int n = 0; n < 4; ++n) {
      int col = wave * 64 + n * 16 + (lane & 15);
      as_v[n] = As[col]; ad_v[n] = Ad[col];
    }
#pragma unroll
    for (int m = 0; m < 4; ++m) {
#pragma unroll
      for (int i = 0; i < 4; ++i) {
        float ps = 0.f, pd = 0.f;
#pragma unroll
        for (int n = 0; n < 4; ++n) {
          ps += acc[m][n][i] * as_v[n];
          pd += acc[m][n][i] * ad_v[n];
        }
#pragma unroll
        for (int off = 1; off <= 8; off <<= 1) {
          ps += __shfl_xor(ps, off);
          pd += __shfl_xor(pd, off);
        }
        if ((lane & 15) == 0) {
          int row_loc = (lane >> 4) * 4 + i + m * 16;
          eS[row_loc][wave] = ps;
          eD[row_loc][wave] = pd;
        }
      }
    }
  }
  __syncthreads();
  if (tid < 64) {
    float s = 0.f, d = 0.f;
#pragma unroll
    for (int w = 0; w < 8; ++w) { s += eS[tid][w]; d += eD[tid][w]; }
    es[mBase + tid] = s;
    ed[mBase + tid] = d;
  }

  const int orow0 = mBase + (lane >> 4) * 4;
#pragma unroll
  for (int m = 0; m < 4; ++m) {
#pragma unroll
    for (int n = 0; n < 4; ++n) {
      int col = wave * 64 + n * 16 + (lane & 15);
#pragma unroll
      for (int i = 0; i < 4; ++i)
        H[(size_t)(orow0 + m * 16 + i) * F_ + col] = acc[m][n][i];
    }
  }
}

// ---------- fallback: h_gemm R12 + e_kernel (validated) ----------
__global__ __launch_bounds__(256, 3) void h_gemm(const float* __restrict__ X,
                                                 const _Float16* __restrict__ Wt2,
                                                 float* __restrict__ H) {
  __shared__ _Float16 Al[2][64][40];
  const int mBase = blockIdx.y * 64;
  const int nBase = blockIdx.x * 256;
  const int tid  = threadIdx.x;
  const int lane = tid & 63;
  const int wave = tid >> 6;
  const int fr_row = lane & 15;
  const int fr_k   = (lane >> 4) * 8;
  const int ar = tid >> 2;
  const int ak = (tid & 3) * 8;
  f32x4 acc[4][4] = {};

  const _Float16* Bb = Wt2 + (size_t)(nBase + wave * 64 + fr_row) * 32 + fr_k;
  const size_t PSTRIDE = (size_t)F_ * 32;

  f16x8 bf[4];
#pragma unroll
  for (int n = 0; n < 4; ++n) bf[n] = *(const f16x8*)&Bb[(size_t)n * 512];

  {
    float4 a0 = *(const float4*)&X[(size_t)(mBase + ar) * D_ + ak];
    float4 a1 = *(const float4*)&X[(size_t)(mBase + ar) * D_ + ak + 4];
    f16x8 ah = { (_Float16)a0.x, (_Float16)a0.y, (_Float16)a0.z, (_Float16)a0.w,
                 (_Float16)a1.x, (_Float16)a1.y, (_Float16)a1.z, (_Float16)a1.w };
    *(f16x8*)&Al[0][ar][ak] = ah;
  }
  __syncthreads();

  for (int t = 0; t < 64; ++t) {
    const int cur = t & 1;
    float4 na0, na1; f16x8 nb[4];
    if (t < 63) {
      const int k0 = (t + 1) * 32;
      na0 = *(const float4*)&X[(size_t)(mBase + ar) * D_ + k0 + ak];
      na1 = *(const float4*)&X[(size_t)(mBase + ar) * D_ + k0 + ak + 4];
      const _Float16* bp = Bb + (size_t)(t + 1) * PSTRIDE;
#pragma unroll
      for (int n = 0; n < 4; ++n) nb[n] = *(const f16x8*)&bp[(size_t)n * 512];
    }
    f16x8 af[4];
#pragma unroll
    for (int m = 0; m < 4; ++m) af[m] = *(const f16x8*)&Al[cur][m * 16 + fr_row][fr_k];
#pragma unroll
    for (int m = 0; m < 4; ++m)
#pragma unroll
      for (int n = 0; n < 4; ++n)
        acc[m][n] = __builtin_amdgcn_mfma_f32_16x16x32_f16(af[m], bf[n], acc[m][n], 0, 0, 0);
    if (t < 63) {
      f16x8 ah = { (_Float16)na0.x, (_Float16)na0.y, (_Float16)na0.z, (_Float16)na0.w,
                   (_Float16)na1.x, (_Float16)na1.y, (_Float16)na1.z, (_Float16)na1.w };
      *(f16x8*)&Al[cur ^ 1][ar][ak] = ah;
#pragma unroll
      for (int n = 0; n < 4; ++n) bf[n] = nb[n];
    }
    __syncthreads();
  }

  const int orow0 = mBase + (lane >> 4) * 4;
#pragma unroll
  for (int m = 0; m < 4; ++m) {
#pragma unroll
    for (int n = 0; n < 4; ++n) {
      int col = nBase + wave * 64 + n * 16 + (lane & 15);
#pragma unroll
      for (int i = 0; i < 4; ++i)
        H[(size_t)(orow0 + m * 16 + i) * F_ + col] = acc[m][n][i];
    }
  }
}

__global__ __launch_bounds__(256) void e_kernel(const float* __restrict__ H,
                                                const float* __restrict__ as,
                                                const float* __restrict__ ad,
                                                float* __restrict__ es,
                                                float* __restrict__ ed) {
  int row  = blockIdx.x * 4 + (threadIdx.x >> 6);
  int lane = threadIdx.x & 63;
  const float* h = H + (size_t)row * F_;
  float s = 0.f, d = 0.f;
#pragma unroll
  for (int p = 0; p < 2; ++p) {
    int col = p * 256 + lane * 4;
    float4 hv = *(const float4*)&h[col];
    float4 av = *(const float4*)&as[col];
    float4 dv = *(const float4*)&ad[col];
    s += hv.x * av.x + hv.y * av.y + hv.z * av.z + hv.w * av.w;
    d += hv.x * dv.x + hv.y * dv.y + hv.z * dv.z + hv.w * dv.w;
  }
  s = wave_reduce_sum(s);
  d = wave_reduce_sum(d);
  if (lane == 0) { es[row] = s; ed[row] = d; }
}

// ---------- kNN screen R12 (fallback path, validated) ----------
__global__ __launch_bounds__(256, 3) void knn_screen(const float* __restrict__ X,
                                                     int* __restrict__ cand8,
                                                     float* __restrict__ gapw) {
  __shared__ _Float16 T[2][256][40];
  __shared__ float sqA[256];

  const int bi  = blockIdx.x;
  const int xcd = bi & 7;
  const int kk  = bi >> 3;
  const int b   = ((kk >> 2) << 3) | xcd;
  const int i0  = (kk & 3) * 64;

  const int tid  = threadIdx.x;
  const int lane = tid & 63;
  const int wave = tid >> 6;
  const float* Xb = X + (size_t)b * N_ * D_;
  const int fr_row = lane & 15;
  const int fr_k   = (lane >> 4) * 8;
  const int srow = tid >> 3;
  const int skk  = (tid & 7) * 4;

  f32x4 acc[13] = {};
  float sqp[8] = {};

  {
    float4 v[8];
#pragma unroll
    for (int p = 0; p < 8; ++p) {
      int r = p * 32 + srow;
      v[p] = make_float4(0.f, 0.f, 0.f, 0.f);
      if (r < N_) v[p] = *(const float4*)&Xb[(size_t)r * D_ + skk];
    }
#pragma unroll
    for (int p = 0; p < 8; ++p) {
      int r = p * 32 + srow;
      sqp[p] += v[p].x * v[p].x + v[p].y * v[p].y + v[p].z * v[p].z + v[p].w * v[p].w;
      f16x4 h4 = { (_Float16)v[p].x, (_Float16)v[p].y, (_Float16)v[p].z, (_Float16)v[p].w };
      *(f16x4*)&T[0][r][skk] = h4;
    }
  }
  __syncthreads();

  for (int t = 0; t < 64; ++t) {
    const int cur = t & 1;
    float4 nv[8];
    if (t < 63) {
      const int k0 = (t + 1) * 32;
#pragma unroll
      for (int p = 0; p < 8; ++p) {
        int r = p * 32 + srow;
        nv[p] = make_float4(0.f, 0.f, 0.f, 0.f);
        if (r < N_) nv[p] = *(const float4*)&Xb[(size_t)r * D_ + k0 + skk];
      }
    }
    f16x8 a0 = *(const f16x8*)&T[cur][i0 + wave * 16 + fr_row][fr_k];
#pragma unroll
    for (int n = 0; n < 13; ++n) {
      f16x8 bfr = *(const f16x8*)&T[cur][n * 16 + fr_row][fr_k];
      acc[n] = __builtin_amdgcn_mfma_f32_16x16x32_f16(a0, bfr, acc[n], 0, 0, 0);
    }
    if (t < 63) {
#pragma unroll
      for (int p = 0; p < 8; ++p) {
        int r = p * 32 + srow;
        sqp[p] += nv[p].x * nv[p].x + nv[p].y * nv[p].y + nv[p].z * nv[p].z + nv[p].w * nv[p].w;
        f16x4 h4 = { (_Float16)nv[p].x, (_Float16)nv[p].y, (_Float16)nv[p].z, (_Float16)nv[p].w };
        *(f16x4*)&T[cur ^ 1][r][skk] = h4;
      }
    }
    __syncthreads();
  }

#pragma unroll
  for (int p = 0; p < 8; ++p) {
    float s = sqp[p];
    s += __shfl_xor(s, 1); s += __shfl_xor(s, 2); s += __shfl_xor(s, 4);
    if ((lane & 7) == 0) sqA[p * 32 + srow] = s;
  }
  __syncthreads();

  float sqv[13];
#pragma unroll
  for (int n = 0; n < 13; ++n) sqv[n] = sqA[n * 16 + (lane & 15)];
  const int g = lane >> 4;
#pragma unroll
  for (int i = 0; i < 4; ++i) {
    int row_loc = wave * 16 + g * 4 + i;
    float w13[13];
#pragma unroll
    for (int n = 0; n < 13; ++n) {
      int col = n * 16 + (lane & 15);
      w13[n] = (col < N_) ? (sqv[n] - 2.0f * acc[n][i]) : 1e30f;
    }
    int candv[CAND]; float mscv[CAND];
#pragma unroll
    for (int it = 0; it < CAND; ++it) {
      float mv = w13[0]; int mn = 0;
#pragma unroll
      for (int n = 1; n < 13; ++n)
        if (w13[n] < mv) { mv = w13[n]; mn = n; }
      int mcol = mn * 16 + (lane & 15);
#pragma unroll
      for (int off = 1; off <= 8; off <<= 1) {
        float ov = __shfl_xor(mv, off);
        int   oc = __shfl_xor(mcol, off);
        if (ov < mv || (ov == mv && oc < mcol)) { mv = ov; mcol = oc; }
      }
      mscv[it] = mv; candv[it] = mcol;
      int kn = mcol >> 4;
#pragma unroll
      for (int n = 0; n < 13; ++n)
        if (n == kn && (lane & 15) == (mcol & 15)) w13[n] = 1e30f;
    }
    int ig = i0 + row_loc;
    if ((lane & 15) == 0 && ig < N_) {
      size_t o = ((size_t)b * N_ + ig) * CAND;
#pragma unroll
      for (int c = 0; c < CAND; ++c) cand8[o + c] = candv[c];
      gapw[b * N_ + ig] = mscv[5] - mscv[4];
    }
  }
}

// ---------- kNN screen PAN v2: 2 blocks/batch, 2 row-groups per wave
//            (acc0/acc1 share the 13 B-fragment loads -> 26 MFMA / 15 loads) ----------
__global__ __launch_bounds__(256) void knn_screen_pan(const _Float16* __restrict__ Xh,
                                                      const float* __restrict__ sqg,
                                                      int* __restrict__ cand8,
                                                      float* __restrict__ gapw) {
  const int bi  = blockIdx.x;          // 512 blocks: 2 per batch, XCD-grouped
  const int xcd = bi & 7;
  const int kk  = bi >> 3;
  const int b   = ((kk >> 1) << 3) | xcd;
  const int i0  = (kk & 1) * 128;      // row-half base

  const int tid  = threadIdx.x;
  const int lane = tid & 63;
  const int wave = tid >> 6;           // 0..3
  const int fr_row = lane & 15;
  const int fr_k   = (lane >> 4) * 8;

  const int rg0 = i0 + wave * 16;          // first row-group
  const int rg1 = i0 + 64 + wave * 16;     // second row-group
  if (rg0 >= N_) return;                   // wave-uniform (implies rg1 too)
  const bool do1 = (rg1 < N_);             // wave-uniform

  const _Float16* Pb = Xh + (size_t)b * 64 * PELEMS;
  const int aoff0 = (rg0 + fr_row) * 32 + fr_k;   // max row 207 < PROWS
  const int aoff1 = (rg1 + fr_row) * 32 + fr_k;

  f32x4 acc0[13] = {};
  f32x4 acc1[13] = {};
#pragma unroll 2
  for (int t = 0; t < 64; ++t) {
    const _Float16* P = Pb + (size_t)t * PELEMS;
    f16x8 a0 = *(const f16x8*)&P[aoff0];
    f16x8 a1 = a0;
    if (do1) a1 = *(const f16x8*)&P[aoff1];
#pragma unroll
    for (int n = 0; n < 13; ++n) {
      f16x8 bfr = *(const f16x8*)&P[(n * 16 + fr_row) * 32 + fr_k];
      acc0[n] = __builtin_amdgcn_mfma_f32_16x16x32_f16(a0, bfr, acc0[n], 0, 0, 0);
      if (do1)
        acc1[n] = __builtin_amdgcn_mfma_f32_16x16x32_f16(a1, bfr, acc1[n], 0, 0, 0);
    }
  }

  float sqv[13];
#pragma unroll
  for (int n = 0; n < 13; ++n) {
    int col = n * 16 + (lane & 15);
    sqv[n] = (col < N_) ? sqg[b * N_ + col] : 0.f;
  }
  const int g = lane >> 4;

  // ---- selection for row-group 0 (acc0) ----
#pragma unroll
  for (int i = 0; i < 4; ++i) {
    int ig = rg0 + g * 4 + i;
    float w13[13];
#pragma unroll
    for (int n = 0; n < 13; ++n) {
      int col = n * 16 + (lane & 15);
      w13[n] = (col < N_) ? (sqv[n] - 2.0f * acc0[n][i]) : 1e30f;
    }
    int candv[CAND]; float mscv[CAND];
#pragma unroll
    for (int it = 0; it < CAND; ++it) {
      float mv = w13[0]; int mn = 0;
#pragma unroll
      for (int n = 1; n < 13; ++n)
        if (w13[n] < mv) { mv = w13[n]; mn = n; }
      int mcol = mn * 16 + (lane & 15);
#pragma unroll
      for (int off = 1; off <= 8; off <<= 1) {
        float ov = __shfl_xor(mv, off);
        int   oc = __shfl_xor(mcol, off);
        if (ov < mv || (ov == mv && oc < mcol)) { mv = ov; mcol = oc; }
      }
      mscv[it] = mv; candv[it] = mcol;
      int kn = mcol >> 4;
#pragma unroll
      for (int n = 0; n < 13; ++n)
        if (n == kn && (lane & 15) == (mcol & 15)) w13[n] = 1e30f;
    }
    if ((lane & 15) == 0 && ig < N_) {
      size_t o = ((size_t)b * N_ + ig) * CAND;
#pragma unroll
      for (int c = 0; c < CAND; ++c) cand8[o + c] = candv[c];
      gapw[b * N_ + ig] = mscv[5] - mscv[4];
    }
  }

  // ---- selection for row-group 1 (acc1) ----
  if (do1) {
#pragma unroll
    for (int i = 0; i < 4; ++i) {
      int ig = rg1 + g * 4 + i;
      float w13[13];
#pragma unroll
      for (int n = 0; n < 13; ++n) {
        int col = n * 16 + (lane & 15);
        w13[n] = (col < N_) ? (sqv[n] - 2.0f * acc1[n][i]) : 1e30f;
      }
      int candv[CAND]; float mscv[CAND];
#pragma unroll
      for (int it = 0; it < CAND; ++it) {
        float mv = w13[0]; int mn = 0;
#pragma unroll
        for (int n = 1; n < 13; ++n)
          if (w13[n] < mv) { mv = w13[n]; mn = n; }
        int mcol = mn * 16 + (lane & 15);
#pragma unroll
        for (int off = 1; off <= 8; off <<= 1) {
          float ov = __shfl_xor(mv, off);
          int   oc = __shfl_xor(mcol, off);
          if (ov < mv || (ov == mv && oc < mcol)) { mv = ov; mcol = oc; }
        }
        mscv[it] = mv; candv[it] = mcol;
        int kn = mcol >> 4;
#pragma unroll
        for (int n = 0; n < 13; ++n)
          if (n == kn && (lane & 15) == (mcol & 15)) w13[n] = 1e30f;
      }
      if ((lane & 15) == 0 && ig < N_) {
        size_t o = ((size_t)b * N_ + ig) * CAND;
#pragma unroll
        for (int c = 0; c < CAND; ++c) cand8[o + c] = candv[c];
        gapw[b * N_ + ig] = mscv[5] - mscv[4];
      }
    }
  }
}

// ---------- kNN resolve + FUSED agg: one wave per row; 3-tier; writes out directly ----------
__global__ __launch_bounds__(256) void knn_resolve(const float* __restrict__ X,
                                                   const float* __restrict__ H,
                                                   const int* __restrict__ cand8,
                                                   const float* __restrict__ gapw,
                                                   const float* __restrict__ es,
                                                   const float* __restrict__ ed,
                                                   float* __restrict__ out) {
  const int gr   = blockIdx.x * 4 + (threadIdx.x >> 6);
  const int lane = threadIdx.x & 63;
  const int b    = gr / N_;
  const int ig   = gr - b * N_;
  const float* Xb = X + (size_t)b * N_ * D_;
  const float* xi = Xb + (size_t)ig * D_;

  int cand[CAND];
#pragma unroll
  for (int c = 0; c < CAND; ++c) cand[c] = cand8[(size_t)gr * CAND + c];
  float gap = gapw[gr];

  int ordj[5];
  if (gap > 0.75f) {
#pragma unroll
    for (int m5 = 0; m5 < 5; ++m5) ordj[m5] = cand[m5];
  } else {
    float4 xr[8];
#pragma unroll
    for (int q = 0; q < 8; ++q) xr[q] = *(const float4*)&xi[q * 256 + lane * 4];
    double s8[CAND];
#pragma unroll
    for (int c = 0; c < CAND; ++c) {
      const float* xj = Xb + (size_t)cand[c] * D_;
      double dsum = 0.0, sqc = 0.0;
#pragma unroll
      for (int q = 0; q < 8; ++q) {
        float4 u = *(const float4*)&xj[q * 256 + lane * 4];
        dsum += (double)xr[q].x * (double)u.x + (double)xr[q].y * (double)u.y
              + (double)xr[q].z * (double)u.z + (double)xr[q].w * (double)u.w;
        sqc  += (double)u.x * (double)u.x + (double)u.y * (double)u.y
              + (double)u.z * (double)u.z + (double)u.w * (double)u.w;
      }
      dsum = wave_reduce_sum_d(dsum);
      sqc  = wave_reduce_sum_d(sqc);
      s8[c] = sqc - 2.0 * dsum;
    }
    int rnk[CAND];
#pragma unroll
    for (int c = 0; c < CAND; ++c) {
      int r = 0;
#pragma unroll
      for (int c2 = 0; c2 < CAND; ++c2)
        if (c2 != c && (s8[c2] < s8[c] || (s8[c2] == s8[c] && cand[c2] < cand[c]))) r++;
      rnk[c] = r;
    }
    double g5 = 0.0, g6 = 0.0;
#pragma unroll
    for (int c = 0; c < CAND; ++c) {
      if (rnk[c] == 4) g5 = s8[c];
      if (rnk[c] == 5) g6 = s8[c];
    }
#pragma unroll
    for (int m5 = 0; m5 < 5; ++m5) {
      int oj = 0;
#pragma unroll
      for (int c = 0; c < CAND; ++c)
        if (rnk[c] == m5) oj = cand[c];
      ordj[m5] = oj;
    }
    if (!(g6 - g5 > 4e-3)) {
      float sqi_ex = np_sq_row(xi, lane);
      float sqc_ex[CAND];
#pragma unroll
      for (int c = 0; c < CAND; ++c)
        sqc_ex[c] = np_sq_row(Xb + (size_t)cand[c] * D_, lane);
      int grp8 = (lane >> 2) & 7;
      int l4 = lane & 3;
      int cj = cand[0];
#pragma unroll
      for (int c = 1; c < CAND; ++c)
        if (grp8 == c) cj = cand[c];
      const float* xjr = Xb + (size_t)cj * D_;
      float aacc = 0.f;
      for (int s5 = 0; s5 < 512; ++s5) {
        int d = s5 * 4 + l4;
        aacc = __fadd_rn(aacc, __fmul_rn(xi[d], xjr[d]));
      }
      float d2c[CAND];
#pragma unroll
      for (int c = 0; c < CAND; ++c) {
        float s0 = __shfl(aacc, c * 4 + 0);
        float s1 = __shfl(aacc, c * 4 + 1);
        float s2 = __shfl(aacc, c * 4 + 2);
        float s3 = __shfl(aacc, c * 4 + 3);
        float G  = __fadd_rn(__fadd_rn(s0, s1), __fadd_rn(s2, s3));
        float Sij = __fadd_rn(sqi_ex, sqc_ex[c]);
        d2c[c] = __fsub_rn(Sij, __fadd_rn(G, G));
      }
      int rnk3[CAND];
#pragma unroll
      for (int c = 0; c < CAND; ++c) {
        int r = 0;
#pragma unroll
        for (int c2 = 0; c2 < CAND; ++c2)
          if (c2 != c && (d2c[c2] < d2c[c] || (d2c[c2] == d2c[c] && cand[c2] < cand[c]))) r++;
        rnk3[c] = r;
      }
#pragma unroll
      for (int m5 = 0; m5 < 5; ++m5) {
        int oj = 0;
#pragma unroll
        for (int c = 0; c < CAND; ++c)
          if (rnk3[c] == m5) oj = cand[c];
        ordj[m5] = oj;
      }
    }
  }
  // softmax over leaky_relu(e_src[i]+e_dst[j]) of the 5 neighbors
  float ei = es[gr];
  float ev[5];
#pragma unroll
  for (int m5 = 0; m5 < 5; ++m5) {
    float e = ei + ed[b * N_ + ordj[m5]];
    ev[m5] = e > 0.f ? e : 0.2f * e;
  }
  float mx = fmaxf(fmaxf(fmaxf(ev[0], ev[1]), fmaxf(ev[2], ev[3])), ev[4]);
  float p0 = expf(ev[0] - mx), p1 = expf(ev[1] - mx), p2 = expf(ev[2] - mx),
        p3 = expf(ev[3] - mx), p4 = expf(ev[4] - mx);
  float inv = 1.0f / (p0 + p1 + p2 + p3 + p4);
  float al[5] = { p0 * inv, p1 * inv, p2 * inv, p3 * inv, p4 * inv };

  // ---- fused aggregation: lane owns 8 consecutive output floats ----
  const float* Hb = H + (size_t)b * N_ * F_;
  float a0x = 0.f, a0y = 0.f, a0z = 0.f, a0w = 0.f;
  float a1x = 0.f, a1y = 0.f, a1z = 0.f, a1w = 0.f;
#pragma unroll
  for (int c = 0; c < 5; ++c) {
    const float* hr = Hb + (size_t)ordj[c] * F_ + lane * 8;
    float4 h0 = *(const float4*)hr;
    float4 h1 = *(const float4*)(hr + 4);
    float a = al[c];
    a0x += a * h0.x; a0y += a * h0.y; a0z += a * h0.z; a0w += a * h0.w;
    a1x += a * h1.x; a1y += a * h1.y; a1z += a * h1.z; a1w += a * h1.w;
  }
  float4 o0, o1;
  o0.x = a0x > 0.f ? a0x : expf(a0x) - 1.f;
  o0.y = a0y > 0.f ? a0y : expf(a0y) - 1.f;
  o0.z = a0z > 0.f ? a0z : expf(a0z) - 1.f;
  o0.w = a0w > 0.f ? a0w : expf(a0w) - 1.f;
  o1.x = a1x > 0.f ? a1x : expf(a1x) - 1.f;
  o1.y = a1y > 0.f ? a1y : expf(a1y) - 1.f;
  o1.z = a1z > 0.f ? a1z : expf(a1z) - 1.f;
  o1.w = a1w > 0.f ? a1w : expf(a1w) - 1.f;
  float* op = out + (size_t)gr * F_ + lane * 8;
  *(float4*)op = o0;
  *(float4*)(op + 4) = o1;
}

extern "C" void kernel_launch(void* const* d_in, const int* in_sizes, int n_in,
                              void* d_out, int out_size, void* d_ws, size_t ws_size,
                              hipStream_t stream) {
  const float* X    = (const float*)d_in[0];
  const float* W    = (const float*)d_in[1];
  const float* Asrc = (const float*)d_in[2];
  const float* Adst = (const float*)d_in[3];
  float* out = (float*)d_out;

  const size_t OFF_WT  = 0;                       // 2,097,152 (Wt2 k-panels)
  const size_t OFF_ES  = OFF_WT + 2097152;
  const size_t OFF_ED  = OFF_ES + 200704;
  const size_t OFF_C8  = OFF_ED + 200704;         // 50176*8*4
  const size_t OFF_GAP = OFF_C8 + 1605632;
  const size_t OFF_SQG = OFF_GAP + 200704;        // 50176*4
  const size_t OFF_H   = OFF_SQG + 200704;        // 102,760,448
  const size_t OFF_XH  = OFF_H + (size_t)ROWS * F_ * 4;
  const size_t XH_BYTES = (size_t)B_ * 64 * PELEMS * 2;   // 218,103,808
  const size_t NEED_A  = OFF_XH;
  const size_t NEED_B  = OFF_XH + XH_BYTES;
  if (ws_size < NEED_A) return;

  char* ws = (char*)d_ws;
  _Float16* Wt2 = (_Float16*)(ws + OFF_WT);
  float* es     = (float*)(ws + OFF_ES);
  float* ed     = (float*)(ws + OFF_ED);
  int*   cand8  = (int*)  (ws + OFF_C8);
  float* gapw   = (float*)(ws + OFF_GAP);
  float* sqg    = (float*)(ws + OFF_SQG);
  float* H      = (float*)(ws + OFF_H);
  _Float16* Xh  = (_Float16*)(ws + OFF_XH);

  wtrans_kernel<<<dim3(32, 8), 256, 0, stream>>>(W, Wt2);
  if (ws_size >= NEED_B) {
    h_gemm_pan<<<784, 512, 0, stream>>>(X, Wt2, Asrc, Adst, H, Xh, sqg, es, ed);
    knn_screen_pan<<<512, 256, 0, stream>>>(Xh, sqg, cand8, gapw);
  } else {
    h_gemm<<<dim3(2, 784), 256, 0, stream>>>(X, Wt2, H);
    e_kernel<<<ROWS / 4, 256, 0, stream>>>(H, Asrc, Adst, es, ed);
    knn_screen<<<1024, 256, 0, stream>>>(X, cand8, gapw);
  }
  knn_resolve<<<ROWS / 4, 256, 0, stream>>>(X, H, cand8, gapw, es, ed, out);
}

// Round 21
// 605.725 us; speedup vs baseline: 1.6699x; 1.0260x over previous
//
#include <hip/hip_runtime.h>

#define B_  256
#define N_  196
#define D_  2048
#define F_  512
#define ROWS (B_*N_)   // 50176
#define CAND 8
#define PROWS 208
#define PELEMS (PROWS*32)   // 6656 fp16 per panel

typedef _Float16 f16x8 __attribute__((ext_vector_type(8)));
typedef _Float16 f16x4 __attribute__((ext_vector_type(4)));
typedef float    f32x4 __attribute__((ext_vector_type(4)));

static __device__ __forceinline__ float wave_reduce_sum(float v) {
#pragma unroll
  for (int off = 32; off > 0; off >>= 1) v += __shfl_xor(v, off);
  return v;
}

static __device__ __forceinline__ double wave_reduce_sum_d(double v) {
#pragma unroll
  for (int off = 32; off > 0; off >>= 1) v += __shfl_xor(v, off);
  return v;
}

// numpy pairwise-sum replica of sum(x*x) (R5-validated, bit-exact).
static __device__ __forceinline__ float np_chain16(const float* __restrict__ x, int h) {
  int base = (h >> 3) * 128 + (h & 7);
  float t0 = x[base];
  float r = __fmul_rn(t0, t0);
#pragma unroll
  for (int i = 1; i < 16; ++i) {
    float t = x[base + 8 * i];
    r = __fadd_rn(r, __fmul_rn(t, t));
  }
  return r;
}
static __device__ __forceinline__ float np_sq_row(const float* __restrict__ x, int lane) {
  float ra = np_chain16(x, lane);
  float rb = np_chain16(x, lane + 64);
#pragma unroll
  for (int off = 1; off <= 4; off <<= 1) {
    ra = __fadd_rn(ra, __shfl_xor(ra, off));
    rb = __fadd_rn(rb, __shfl_xor(rb, off));
  }
  float lf[16];
#pragma unroll
  for (int L = 0; L < 8; ++L) { lf[L] = __shfl(ra, L * 8); lf[8 + L] = __shfl(rb, L * 8); }
  float b8[8];
#pragma unroll
  for (int t = 0; t < 8; ++t) b8[t] = __fadd_rn(lf[2 * t], lf[2 * t + 1]);
  float c4[4];
#pragma unroll
  for (int t = 0; t < 4; ++t) c4[t] = __fadd_rn(b8[2 * t], b8[2 * t + 1]);
  return __fadd_rn(__fadd_rn(c4[0], c4[1]), __fadd_rn(c4[2], c4[3]));
}

// ---------- W [K][F] fp32  ->  Wt2 k-panels: [K/32][F][32] fp16 ----------
__global__ __launch_bounds__(256) void wtrans_kernel(const float* __restrict__ W,
                                                     _Float16* __restrict__ Wt2) {
  __shared__ float T[64][68];
  int k0 = blockIdx.x * 64;
  int f0 = blockIdx.y * 64;
  int tid = threadIdx.x;
  int c = tid & 63;
  int r4 = tid >> 6;
#pragma unroll
  for (int p = 0; p < 16; ++p) {
    int r = p * 4 + r4;
    T[r][c] = W[(size_t)(k0 + r) * F_ + f0 + c];
  }
  __syncthreads();
#pragma unroll
  for (int p = 0; p < 16; ++p) {
    int fr = p * 4 + r4;
    int kg = k0 + c;
    Wt2[(size_t)(kg >> 5) * F_ * 32 + (size_t)(f0 + fr) * 32 + (kg & 31)] = (_Float16)T[c][fr];
  }
}

// ---------- h_gemm_pan (R15/R17-validated) + fused e_src/e_dst ----------
__global__ __launch_bounds__(512, 2) void h_gemm_pan(const float* __restrict__ X,
                                                     const _Float16* __restrict__ Wt2,
                                                     const float* __restrict__ As,
                                                     const float* __restrict__ Ad,
                                                     float* __restrict__ H,
                                                     _Float16* __restrict__ Xh,
                                                     float* __restrict__ sqg,
                                                     float* __restrict__ es,
                                                     float* __restrict__ ed) {
  __shared__ _Float16 Al[2][64][40];
  __shared__ float eS[64][8];
  __shared__ float eD[64][8];
  const int mBase = blockIdx.x * 64;
  const int tid  = threadIdx.x;
  const int lane = tid & 63;
  const int wave = tid >> 6;           // 0..7, owns cols wave*64..+63
  const int fr_row = lane & 15;
  const int fr_k   = (lane >> 4) * 8;
  const int ar = tid >> 3;             // 0..63 (A staging row)
  const int ak = (tid & 7) * 4;        // 0,4,...,28 (A staging col)
  f32x4 acc[4][4] = {};
  float sqp = 0.f;

  const int grow = mBase + ar;
  const int bb = grow / N_;
  const int rl = grow - bb * N_;
  _Float16* pRow = Xh + (size_t)bb * 64 * PELEMS + (size_t)rl * 32 + ak;

  const _Float16* Bb = Wt2 + (size_t)(wave * 64 + fr_row) * 32 + fr_k;
  const size_t PSTRIDE = (size_t)F_ * 32;

  f16x8 bf[4];
#pragma unroll
  for (int n = 0; n < 4; ++n) bf[n] = *(const f16x8*)&Bb[(size_t)n * 512];

  {
    float4 a0 = *(const float4*)&X[(size_t)grow * D_ + ak];
    f16x4 ah = { (_Float16)a0.x, (_Float16)a0.y, (_Float16)a0.z, (_Float16)a0.w };
    *(f16x4*)&Al[0][ar][ak] = ah;
    sqp += a0.x * a0.x + a0.y * a0.y + a0.z * a0.z + a0.w * a0.w;
    *(f16x4*)pRow = ah;                 // panel 0
  }
  __syncthreads();

  for (int t = 0; t < 64; ++t) {
    const int cur = t & 1;
    float4 na; f16x8 nb[4];
    if (t < 63) {
      const int k0 = (t + 1) * 32;
      na = *(const float4*)&X[(size_t)grow * D_ + k0 + ak];
      const _Float16* bp = Bb + (size_t)(t + 1) * PSTRIDE;
#pragma unroll
      for (int n = 0; n < 4; ++n) nb[n] = *(const f16x8*)&bp[(size_t)n * 512];
    }
    f16x8 af[4];
#pragma unroll
    for (int m = 0; m < 4; ++m) af[m] = *(const f16x8*)&Al[cur][m * 16 + fr_row][fr_k];
#pragma unroll
    for (int m = 0; m < 4; ++m)
#pragma unroll
      for (int n = 0; n < 4; ++n)
        acc[m][n] = __builtin_amdgcn_mfma_f32_16x16x32_f16(af[m], bf[n], acc[m][n], 0, 0, 0);
    if (t < 63) {
      f16x4 nah = { (_Float16)na.x, (_Float16)na.y, (_Float16)na.z, (_Float16)na.w };
      *(f16x4*)&Al[cur ^ 1][ar][ak] = nah;
      sqp += na.x * na.x + na.y * na.y + na.z * na.z + na.w * na.w;
      *(f16x4*)(pRow + (size_t)(t + 1) * PELEMS) = nah;   // panel t+1
#pragma unroll
      for (int n = 0; n < 4; ++n) bf[n] = nb[n];
    }
    __syncthreads();
  }

  // approx row-norm: 8 staging lanes per row reduce
  {
    float s = sqp;
    s += __shfl_xor(s, 1); s += __shfl_xor(s, 2); s += __shfl_xor(s, 4);
    if ((lane & 7) == 0) sqg[grow] = s;
  }

  // ---- fused e_src/e_dst ----
  {
    float as_v[4], ad_v[4];
#pragma unroll
    for (int n = 0; n < 4; ++n) {
      int col = wave * 64 + n * 16 + (lane & 15);
      as_v[n] = As[col]; ad_v[n] = Ad[col];
    }
#pragma unroll
    for (int m = 0; m < 4; ++m) {
#pragma unroll
      for (int i = 0; i < 4; ++i) {
        float ps = 0.f, pd = 0.f;
#pragma unroll
        for (int n = 0; n < 4; ++n) {
          ps += acc[m][n][i] * as_v[n];
          pd += acc[m][n][i] * ad_v[n];
        }
#pragma unroll
        for (int off = 1; off <= 8; off <<= 1) {
          ps += __shfl_xor(ps, off);
          pd += __shfl_xor(pd, off);
        }
        if ((lane & 15) == 0) {
          int row_loc = (lane >> 4) * 4 + i + m * 16;
          eS[row_loc][wave] = ps;
          eD[row_loc][wave] = pd;
        }
      }
    }
  }
  __syncthreads();
  if (tid < 64) {
    float s = 0.f, d = 0.f;
#pragma unroll
    for (int w = 0; w < 8; ++w) { s += eS[tid][w]; d += eD[tid][w]; }
    es[mBase + tid] = s;
    ed[mBase + tid] = d;
  }

  const int orow0 = mBase + (lane >> 4) * 4;
#pragma unroll
  for (int m = 0; m < 4; ++m) {
#pragma unroll
    for (int n = 0; n < 4; ++n) {
      int col = wave * 64 + n * 16 + (lane & 15);
#pragma unroll
      for (int i = 0; i < 4; ++i)
        H[(size_t)(orow0 + m * 16 + i) * F_ + col] = acc[m][n][i];
    }
  }
}

// ---------- fallback: h_gemm R12 + e_kernel (validated) ----------
__global__ __launch_bounds__(256, 3) void h_gemm(const float* __restrict__ X,
                                                 const _Float16* __restrict__ Wt2,
                                                 float* __restrict__ H) {
  __shared__ _Float16 Al[2][64][40];
  const int mBase = blockIdx.y * 64;
  const int nBase = blockIdx.x * 256;
  const int tid  = threadIdx.x;
  const int lane = tid & 63;
  const int wave = tid >> 6;
  const int fr_row = lane & 15;
  const int fr_k   = (lane >> 4) * 8;
  const int ar = tid >> 2;
  const int ak = (tid & 3) * 8;
  f32x4 acc[4][4] = {};

  const _Float16* Bb = Wt2 + (size_t)(nBase + wave * 64 + fr_row) * 32 + fr_k;
  const size_t PSTRIDE = (size_t)F_ * 32;

  f16x8 bf[4];
#pragma unroll
  for (int n = 0; n < 4; ++n) bf[n] = *(const f16x8*)&Bb[(size_t)n * 512];

  {
    float4 a0 = *(const float4*)&X[(size_t)(mBase + ar) * D_ + ak];
    float4 a1 = *(const float4*)&X[(size_t)(mBase + ar) * D_ + ak + 4];
    f16x8 ah = { (_Float16)a0.x, (_Float16)a0.y, (_Float16)a0.z, (_Float16)a0.w,
                 (_Float16)a1.x, (_Float16)a1.y, (_Float16)a1.z, (_Float16)a1.w };
    *(f16x8*)&Al[0][ar][ak] = ah;
  }
  __syncthreads();

  for (int t = 0; t < 64; ++t) {
    const int cur = t & 1;
    float4 na0, na1; f16x8 nb[4];
    if (t < 63) {
      const int k0 = (t + 1) * 32;
      na0 = *(const float4*)&X[(size_t)(mBase + ar) * D_ + k0 + ak];
      na1 = *(const float4*)&X[(size_t)(mBase + ar) * D_ + k0 + ak + 4];
      const _Float16* bp = Bb + (size_t)(t + 1) * PSTRIDE;
#pragma unroll
      for (int n = 0; n < 4; ++n) nb[n] = *(const f16x8*)&bp[(size_t)n * 512];
    }
    f16x8 af[4];
#pragma unroll
    for (int m = 0; m < 4; ++m) af[m] = *(const f16x8*)&Al[cur][m * 16 + fr_row][fr_k];
#pragma unroll
    for (int m = 0; m < 4; ++m)
#pragma unroll
      for (int n = 0; n < 4; ++n)
        acc[m][n] = __builtin_amdgcn_mfma_f32_16x16x32_f16(af[m], bf[n], acc[m][n], 0, 0, 0);
    if (t < 63) {
      f16x8 ah = { (_Float16)na0.x, (_Float16)na0.y, (_Float16)na0.z, (_Float16)na0.w,
                   (_Float16)na1.x, (_Float16)na1.y, (_Float16)na1.z, (_Float16)na1.w };
      *(f16x8*)&Al[cur ^ 1][ar][ak] = ah;
#pragma unroll
      for (int n = 0; n < 4; ++n) bf[n] = nb[n];
    }
    __syncthreads();
  }

  const int orow0 = mBase + (lane >> 4) * 4;
#pragma unroll
  for (int m = 0; m < 4; ++m) {
#pragma unroll
    for (int n = 0; n < 4; ++n) {
      int col = nBase + wave * 64 + n * 16 + (lane & 15);
#pragma unroll
      for (int i = 0; i < 4; ++i)
        H[(size_t)(orow0 + m * 16 + i) * F_ + col] = acc[m][n][i];
    }
  }
}

__global__ __launch_bounds__(256) void e_kernel(const float* __restrict__ H,
                                                const float* __restrict__ as,
                                                const float* __restrict__ ad,
                                                float* __restrict__ es,
                                                float* __restrict__ ed) {
  int row  = blockIdx.x * 4 + (threadIdx.x >> 6);
  int lane = threadIdx.x & 63;
  const float* h = H + (size_t)row * F_;
  float s = 0.f, d = 0.f;
#pragma unroll
  for (int p = 0; p < 2; ++p) {
    int col = p * 256 + lane * 4;
    float4 hv = *(const float4*)&h[col];
    float4 av = *(const float4*)&as[col];
    float4 dv = *(const float4*)&ad[col];
    s += hv.x * av.x + hv.y * av.y + hv.z * av.z + hv.w * av.w;
    d += hv.x * dv.x + hv.y * dv.y + hv.z * dv.z + hv.w * dv.w;
  }
  s = wave_reduce_sum(s);
  d = wave_reduce_sum(d);
  if (lane == 0) { es[row] = s; ed[row] = d; }
}

// ---------- kNN screen R12 (fallback path, validated) ----------
__global__ __launch_bounds__(256, 3) void knn_screen(const float* __restrict__ X,
                                                     int* __restrict__ cand8,
                                                     float* __restrict__ gapw) {
  __shared__ _Float16 T[2][256][40];
  __shared__ float sqA[256];

  const int bi  = blockIdx.x;
  const int xcd = bi & 7;
  const int kk  = bi >> 3;
  const int b   = ((kk >> 2) << 3) | xcd;
  const int i0  = (kk & 3) * 64;

  const int tid  = threadIdx.x;
  const int lane = tid & 63;
  const int wave = tid >> 6;
  const float* Xb = X + (size_t)b * N_ * D_;
  const int fr_row = lane & 15;
  const int fr_k   = (lane >> 4) * 8;
  const int srow = tid >> 3;
  const int skk  = (tid & 7) * 4;

  f32x4 acc[13] = {};
  float sqp[8] = {};

  {
    float4 v[8];
#pragma unroll
    for (int p = 0; p < 8; ++p) {
      int r = p * 32 + srow;
      v[p] = make_float4(0.f, 0.f, 0.f, 0.f);
      if (r < N_) v[p] = *(const float4*)&Xb[(size_t)r * D_ + skk];
    }
#pragma unroll
    for (int p = 0; p < 8; ++p) {
      int r = p * 32 + srow;
      sqp[p] += v[p].x * v[p].x + v[p].y * v[p].y + v[p].z * v[p].z + v[p].w * v[p].w;
      f16x4 h4 = { (_Float16)v[p].x, (_Float16)v[p].y, (_Float16)v[p].z, (_Float16)v[p].w };
      *(f16x4*)&T[0][r][skk] = h4;
    }
  }
  __syncthreads();

  for (int t = 0; t < 64; ++t) {
    const int cur = t & 1;
    float4 nv[8];
    if (t < 63) {
      const int k0 = (t + 1) * 32;
#pragma unroll
      for (int p = 0; p < 8; ++p) {
        int r = p * 32 + srow;
        nv[p] = make_float4(0.f, 0.f, 0.f, 0.f);
        if (r < N_) nv[p] = *(const float4*)&Xb[(size_t)r * D_ + k0 + skk];
      }
    }
    f16x8 a0 = *(const f16x8*)&T[cur][i0 + wave * 16 + fr_row][fr_k];
#pragma unroll
    for (int n = 0; n < 13; ++n) {
      f16x8 bfr = *(const f16x8*)&T[cur][n * 16 + fr_row][fr_k];
      acc[n] = __builtin_amdgcn_mfma_f32_16x16x32_f16(a0, bfr, acc[n], 0, 0, 0);
    }
    if (t < 63) {
#pragma unroll
      for (int p = 0; p < 8; ++p) {
        int r = p * 32 + srow;
        sqp[p] += nv[p].x * nv[p].x + nv[p].y * nv[p].y + nv[p].z * nv[p].z + nv[p].w * nv[p].w;
        f16x4 h4 = { (_Float16)nv[p].x, (_Float16)nv[p].y, (_Float16)nv[p].z, (_Float16)nv[p].w };
        *(f16x4*)&T[cur ^ 1][r][skk] = h4;
      }
    }
    __syncthreads();
  }

#pragma unroll
  for (int p = 0; p < 8; ++p) {
    float s = sqp[p];
    s += __shfl_xor(s, 1); s += __shfl_xor(s, 2); s += __shfl_xor(s, 4);
    if ((lane & 7) == 0) sqA[p * 32 + srow] = s;
  }
  __syncthreads();

  float sqv[13];
#pragma unroll
  for (int n = 0; n < 13; ++n) sqv[n] = sqA[n * 16 + (lane & 15)];
  const int g = lane >> 4;
#pragma unroll
  for (int i = 0; i < 4; ++i) {
    int row_loc = wave * 16 + g * 4 + i;
    float w13[13];
#pragma unroll
    for (int n = 0; n < 13; ++n) {
      int col = n * 16 + (lane & 15);
      w13[n] = (col < N_) ? (sqv[n] - 2.0f * acc[n][i]) : 1e30f;
    }
    int candv[CAND]; float mscv[CAND];
#pragma unroll
    for (int it = 0; it < CAND; ++it) {
      float mv = w13[0]; int mn = 0;
#pragma unroll
      for (int n = 1; n < 13; ++n)
        if (w13[n] < mv) { mv = w13[n]; mn = n; }
      int mcol = mn * 16 + (lane & 15);
#pragma unroll
      for (int off = 1; off <= 8; off <<= 1) {
        float ov = __shfl_xor(mv, off);
        int   oc = __shfl_xor(mcol, off);
        if (ov < mv || (ov == mv && oc < mcol)) { mv = ov; mcol = oc; }
      }
      mscv[it] = mv; candv[it] = mcol;
      int kn = mcol >> 4;
#pragma unroll
      for (int n = 0; n < 13; ++n)
        if (n == kn && (lane & 15) == (mcol & 15)) w13[n] = 1e30f;
    }
    int ig = i0 + row_loc;
    if ((lane & 15) == 0 && ig < N_) {
      size_t o = ((size_t)b * N_ + ig) * CAND;
#pragma unroll
      for (int c = 0; c < CAND; ++c) cand8[o + c] = candv[c];
      gapw[b * N_ + ig] = mscv[5] - mscv[4];
    }
  }
}

// ---------- kNN screen PAN v3: ONE block per batch (512 thr, 8 waves),
//            each wave owns row-groups {w*16, 128+w*16}; B-frag loads shared ----------
__global__ __launch_bounds__(512) void knn_screen_pan(const _Float16* __restrict__ Xh,
                                                      const float* __restrict__ sqg,
                                                      int* __restrict__ cand8,
                                                      float* __restrict__ gapw) {
  const int b = blockIdx.x;            // one batch per block
  const int tid  = threadIdx.x;
  const int lane = tid & 63;
  const int wave = tid >> 6;           // 0..7
  const int fr_row = lane & 15;
  const int fr_k   = (lane >> 4) * 8;

  const int rg0 = wave * 16;               // rows 0..127 (always valid)
  const int rg1 = 128 + wave * 16;         // rows 128..207 (valid for wave<5)
  const bool do1 = (rg1 < N_);             // wave-uniform

  const _Float16* Pb = Xh + (size_t)b * 64 * PELEMS;
  const int aoff0 = (rg0 + fr_row) * 32 + fr_k;
  const int aoff1 = (rg1 + fr_row) * 32 + fr_k;   // max row 207 < PROWS

  f32x4 acc0[13] = {};
  f32x4 acc1[13] = {};
#pragma unroll 2
  for (int t = 0; t < 64; ++t) {
    const _Float16* P = Pb + (size_t)t * PELEMS;
    f16x8 a0 = *(const f16x8*)&P[aoff0];
    f16x8 a1 = a0;
    if (do1) a1 = *(const f16x8*)&P[aoff1];
#pragma unroll
    for (int n = 0; n < 13; ++n) {
      f16x8 bfr = *(const f16x8*)&P[(n * 16 + fr_row) * 32 + fr_k];
      acc0[n] = __builtin_amdgcn_mfma_f32_16x16x32_f16(a0, bfr, acc0[n], 0, 0, 0);
      if (do1)
        acc1[n] = __builtin_amdgcn_mfma_f32_16x16x32_f16(a1, bfr, acc1[n], 0, 0, 0);
    }
  }

  float sqv[13];
#pragma unroll
  for (int n = 0; n < 13; ++n) {
    int col = n * 16 + (lane & 15);
    sqv[n] = (col < N_) ? sqg[b * N_ + col] : 0.f;
  }
  const int g = lane >> 4;

  // ---- selection for row-group 0 (acc0) ----
#pragma unroll
  for (int i = 0; i < 4; ++i) {
    int ig = rg0 + g * 4 + i;
    float w13[13];
#pragma unroll
    for (int n = 0; n < 13; ++n) {
      int col = n * 16 + (lane & 15);
      w13[n] = (col < N_) ? (sqv[n] - 2.0f * acc0[n][i]) : 1e30f;
    }
    int candv[CAND]; float mscv[CAND];
#pragma unroll
    for (int it = 0; it < CAND; ++it) {
      float mv = w13[0]; int mn = 0;
#pragma unroll
      for (int n = 1; n < 13; ++n)
        if (w13[n] < mv) { mv = w13[n]; mn = n; }
      int mcol = mn * 16 + (lane & 15);
#pragma unroll
      for (int off = 1; off <= 8; off <<= 1) {
        float ov = __shfl_xor(mv, off);
        int   oc = __shfl_xor(mcol, off);
        if (ov < mv || (ov == mv && oc < mcol)) { mv = ov; mcol = oc; }
      }
      mscv[it] = mv; candv[it] = mcol;
      int kn = mcol >> 4;
#pragma unroll
      for (int n = 0; n < 13; ++n)
        if (n == kn && (lane & 15) == (mcol & 15)) w13[n] = 1e30f;
    }
    if ((lane & 15) == 0 && ig < N_) {
      size_t o = ((size_t)b * N_ + ig) * CAND;
#pragma unroll
      for (int c = 0; c < CAND; ++c) cand8[o + c] = candv[c];
      gapw[b * N_ + ig] = mscv[5] - mscv[4];
    }
  }

  // ---- selection for row-group 1 (acc1) ----
  if (do1) {
#pragma unroll
    for (int i = 0; i < 4; ++i) {
      int ig = rg1 + g * 4 + i;
      float w13[13];
#pragma unroll
      for (int n = 0; n < 13; ++n) {
        int col = n * 16 + (lane & 15);
        w13[n] = (col < N_) ? (sqv[n] - 2.0f * acc1[n][i]) : 1e30f;
      }
      int candv[CAND]; float mscv[CAND];
#pragma unroll
      for (int it = 0; it < CAND; ++it) {
        float mv = w13[0]; int mn = 0;
#pragma unroll
        for (int n = 1; n < 13; ++n)
          if (w13[n] < mv) { mv = w13[n]; mn = n; }
        int mcol = mn * 16 + (lane & 15);
#pragma unroll
        for (int off = 1; off <= 8; off <<= 1) {
          float ov = __shfl_xor(mv, off);
          int   oc = __shfl_xor(mcol, off);
          if (ov < mv || (ov == mv && oc < mcol)) { mv = ov; mcol = oc; }
        }
        mscv[it] = mv; candv[it] = mcol;
        int kn = mcol >> 4;
#pragma unroll
        for (int n = 0; n < 13; ++n)
          if (n == kn && (lane & 15) == (mcol & 15)) w13[n] = 1e30f;
      }
      if ((lane & 15) == 0 && ig < N_) {
        size_t o = ((size_t)b * N_ + ig) * CAND;
#pragma unroll
        for (int c = 0; c < CAND; ++c) cand8[o + c] = candv[c];
        gapw[b * N_ + ig] = mscv[5] - mscv[4];
      }
    }
  }
}

// ---------- kNN resolve + FUSED agg: one wave per row; 3-tier; writes out directly ----------
__global__ __launch_bounds__(256) void knn_resolve(const float* __restrict__ X,
                                                   const float* __restrict__ H,
                                                   const int* __restrict__ cand8,
                                                   const float* __restrict__ gapw,
                                                   const float* __restrict__ es,
                                                   const float* __restrict__ ed,
                                                   float* __restrict__ out) {
  const int gr   = blockIdx.x * 4 + (threadIdx.x >> 6);
  const int lane = threadIdx.x & 63;
  const int b    = gr / N_;
  const int ig   = gr - b * N_;
  const float* Xb = X + (size_t)b * N_ * D_;
  const float* xi = Xb + (size_t)ig * D_;

  int cand[CAND];
#pragma unroll
  for (int c = 0; c < CAND; ++c) cand[c] = cand8[(size_t)gr * CAND + c];
  float gap = gapw[gr];

  int ordj[5];
  if (gap > 0.75f) {
#pragma unroll
    for (int m5 = 0; m5 < 5; ++m5) ordj[m5] = cand[m5];
  } else {
    float4 xr[8];
#pragma unroll
    for (int q = 0; q < 8; ++q) xr[q] = *(const float4*)&xi[q * 256 + lane * 4];
    double s8[CAND];
#pragma unroll
    for (int c = 0; c < CAND; ++c) {
      const float* xj = Xb + (size_t)cand[c] * D_;
      double dsum = 0.0, sqc = 0.0;
#pragma unroll
      for (int q = 0; q < 8; ++q) {
        float4 u = *(const float4*)&xj[q * 256 + lane * 4];
        dsum += (double)xr[q].x * (double)u.x + (double)xr[q].y * (double)u.y
              + (double)xr[q].z * (double)u.z + (double)xr[q].w * (double)u.w;
        sqc  += (double)u.x * (double)u.x + (double)u.y * (double)u.y
              + (double)u.z * (double)u.z + (double)u.w * (double)u.w;
      }
      dsum = wave_reduce_sum_d(dsum);
      sqc  = wave_reduce_sum_d(sqc);
      s8[c] = sqc - 2.0 * dsum;
    }
    int rnk[CAND];
#pragma unroll
    for (int c = 0; c < CAND; ++c) {
      int r = 0;
#pragma unroll
      for (int c2 = 0; c2 < CAND; ++c2)
        if (c2 != c && (s8[c2] < s8[c] || (s8[c2] == s8[c] && cand[c2] < cand[c]))) r++;
      rnk[c] = r;
    }
    double g5 = 0.0, g6 = 0.0;
#pragma unroll
    for (int c = 0; c < CAND; ++c) {
      if (rnk[c] == 4) g5 = s8[c];
      if (rnk[c] == 5) g6 = s8[c];
    }
#pragma unroll
    for (int m5 = 0; m5 < 5; ++m5) {
      int oj = 0;
#pragma unroll
      for (int c = 0; c < CAND; ++c)
        if (rnk[c] == m5) oj = cand[c];
      ordj[m5] = oj;
    }
    if (!(g6 - g5 > 4e-3)) {
      float sqi_ex = np_sq_row(xi, lane);
      float sqc_ex[CAND];
#pragma unroll
      for (int c = 0; c < CAND; ++c)
        sqc_ex[c] = np_sq_row(Xb + (size_t)cand[c] * D_, lane);
      int grp8 = (lane >> 2) & 7;
      int l4 = lane & 3;
      int cj = cand[0];
#pragma unroll
      for (int c = 1; c < CAND; ++c)
        if (grp8 == c) cj = cand[c];
      const float* xjr = Xb + (size_t)cj * D_;
      float aacc = 0.f;
      for (int s5 = 0; s5 < 512; ++s5) {
        int d = s5 * 4 + l4;
        aacc = __fadd_rn(aacc, __fmul_rn(xi[d], xjr[d]));
      }
      float d2c[CAND];
#pragma unroll
      for (int c = 0; c < CAND; ++c) {
        float s0 = __shfl(aacc, c * 4 + 0);
        float s1 = __shfl(aacc, c * 4 + 1);
        float s2 = __shfl(aacc, c * 4 + 2);
        float s3 = __shfl(aacc, c * 4 + 3);
        float G  = __fadd_rn(__fadd_rn(s0, s1), __fadd_rn(s2, s3));
        float Sij = __fadd_rn(sqi_ex, sqc_ex[c]);
        d2c[c] = __fsub_rn(Sij, __fadd_rn(G, G));
      }
      int rnk3[CAND];
#pragma unroll
      for (int c = 0; c < CAND; ++c) {
        int r = 0;
#pragma unroll
        for (int c2 = 0; c2 < CAND; ++c2)
          if (c2 != c && (d2c[c2] < d2c[c] || (d2c[c2] == d2c[c] && cand[c2] < cand[c]))) r++;
        rnk3[c] = r;
      }
#pragma unroll
      for (int m5 = 0; m5 < 5; ++m5) {
        int oj = 0;
#pragma unroll
        for (int c = 0; c < CAND; ++c)
          if (rnk3[c] == m5) oj = cand[c];
        ordj[m5] = oj;
      }
    }
  }
  // softmax over leaky_relu(e_src[i]+e_dst[j]) of the 5 neighbors
  float ei = es[gr];
  float ev[5];
#pragma unroll
  for (int m5 = 0; m5 < 5; ++m5) {
    float e = ei + ed[b * N_ + ordj[m5]];
    ev[m5] = e > 0.f ? e : 0.2f * e;
  }
  float mx = fmaxf(fmaxf(fmaxf(ev[0], ev[1]), fmaxf(ev[2], ev[3])), ev[4]);
  float p0 = expf(ev[0] - mx), p1 = expf(ev[1] - mx), p2 = expf(ev[2] - mx),
        p3 = expf(ev[3] - mx), p4 = expf(ev[4] - mx);
  float inv = 1.0f / (p0 + p1 + p2 + p3 + p4);
  float al[5] = { p0 * inv, p1 * inv, p2 * inv, p3 * inv, p4 * inv };

  // ---- fused aggregation: lane owns 8 consecutive output floats ----
  const float* Hb = H + (size_t)b * N_ * F_;
  float a0x = 0.f, a0y = 0.f, a0z = 0.f, a0w = 0.f;
  float a1x = 0.f, a1y = 0.f, a1z = 0.f, a1w = 0.f;
#pragma unroll
  for (int c = 0; c < 5; ++c) {
    const float* hr = Hb + (size_t)ordj[c] * F_ + lane * 8;
    float4 h0 = *(const float4*)hr;
    float4 h1 = *(const float4*)(hr + 4);
    float a = al[c];
    a0x += a * h0.x; a0y += a * h0.y; a0z += a * h0.z; a0w += a * h0.w;
    a1x += a * h1.x; a1y += a * h1.y; a1z += a * h1.z; a1w += a * h1.w;
  }
  float4 o0, o1;
  o0.x = a0x > 0.f ? a0x : expf(a0x) - 1.f;
  o0.y = a0y > 0.f ? a0y : expf(a0y) - 1.f;
  o0.z = a0z > 0.f ? a0z : expf(a0z) - 1.f;
  o0.w = a0w > 0.f ? a0w : expf(a0w) - 1.f;
  o1.x = a1x > 0.f ? a1x : expf(a1x) - 1.f;
  o1.y = a1y > 0.f ? a1y : expf(a1y) - 1.f;
  o1.z = a1z > 0.f ? a1z : expf(a1z) - 1.f;
  o1.w = a1w > 0.f ? a1w : expf(a1w) - 1.f;
  float* op = out + (size_t)gr * F_ + lane * 8;
  *(float4*)op = o0;
  *(float4*)(op + 4) = o1;
}

extern "C" void kernel_launch(void* const* d_in, const int* in_sizes, int n_in,
                              void* d_out, int out_size, void* d_ws, size_t ws_size,
                              hipStream_t stream) {
  const float* X    = (const float*)d_in[0];
  const float* W    = (const float*)d_in[1];
  const float* Asrc = (const float*)d_in[2];
  const float* Adst = (const float*)d_in[3];
  float* out = (float*)d_out;

  const size_t OFF_WT  = 0;                       // 2,097,152 (Wt2 k-panels)
  const size_t OFF_ES  = OFF_WT + 2097152;
  const size_t OFF_ED  = OFF_ES + 200704;
  const size_t OFF_C8  = OFF_ED + 200704;         // 50176*8*4
  const size_t OFF_GAP = OFF_C8 + 1605632;
  const size_t OFF_SQG = OFF_GAP + 200704;        // 50176*4
  const size_t OFF_H   = OFF_SQG + 200704;        // 102,760,448
  const size_t OFF_XH  = OFF_H + (size_t)ROWS * F_ * 4;
  const size_t XH_BYTES = (size_t)B_ * 64 * PELEMS * 2;   // 218,103,808
  const size_t NEED_A  = OFF_XH;
  const size_t NEED_B  = OFF_XH + XH_BYTES;
  if (ws_size < NEED_A) return;

  char* ws = (char*)d_ws;
  _Float16* Wt2 = (_Float16*)(ws + OFF_WT);
  float* es     = (float*)(ws + OFF_ES);
  float* ed     = (float*)(ws + OFF_ED);
  int*   cand8  = (int*)  (ws + OFF_C8);
  float* gapw   = (float*)(ws + OFF_GAP);
  float* sqg    = (float*)(ws + OFF_SQG);
  float* H      = (float*)(ws + OFF_H);
  _Float16* Xh  = (_Float16*)(ws + OFF_XH);

  wtrans_kernel<<<dim3(32, 8), 256, 0, stream>>>(W, Wt2);
  if (ws_size >= NEED_B) {
    h_gemm_pan<<<784, 512, 0, stream>>>(X, Wt2, Asrc, Adst, H, Xh, sqg, es, ed);
    knn_screen_pan<<<B_, 512, 0, stream>>>(Xh, sqg, cand8, gapw);
  } else {
    h_gemm<<<dim3(2, 784), 256, 0, stream>>>(X, Wt2, H);
    e_kernel<<<ROWS / 4, 256, 0, stream>>>(H, Asrc, Adst, es, ed);
    knn_screen<<<1024, 256, 0, stream>>>(X, cand8, gapw);
  }
  knn_resolve<<<ROWS / 4, 256, 0, stream>>>(X, H, cand8, gapw, es, ed, out);
}